// Round 2
// baseline (2487.229 us; speedup 1.0000x reference)
//
#include <hip/hip_runtime.h>
#include <cstdint>

#define NTOK 8192
#define EDIM 768
#define FDIM 3072

using bf16x8 = __attribute__((ext_vector_type(8))) __bf16;
using f32x4  = __attribute__((ext_vector_type(4))) float;

__device__ __forceinline__ float b2f(ushort u){ union{uint32_t i; float f;} v; v.i = ((uint32_t)u)<<16; return v.f; }
__device__ __forceinline__ ushort f2b(float f){ union{float f; uint32_t i;} v; v.f=f; uint32_t r = v.i + 0x7fffu + ((v.i>>16)&1u); return (ushort)(r>>16); }
__device__ __forceinline__ float gelu_f(float v){ return 0.5f*v*(1.0f+erff(v*0.70710678118654752f)); }

__device__ __forceinline__ uint4 fold8(uint4 v, const float* gl, const float* bl, int k){
  union { uint4 q; ushort s[8]; } u; u.q = v;
  f32x4 g0 = *(const f32x4*)(gl+k);
  f32x4 g1 = *(const f32x4*)(gl+k+4);
  f32x4 b0 = *(const f32x4*)(bl+k);
  f32x4 b1 = *(const f32x4*)(bl+k+4);
  #pragma unroll
  for (int i=0;i<4;i++) u.s[i]   = f2b(b2f(u.s[i])  *g0[i] + b0[i]);
  #pragma unroll
  for (int i=0;i<4;i++) u.s[4+i] = f2b(b2f(u.s[4+i])*g1[i] + b1[i]);
  return u.q;
}

// ---------------- weight fp32 -> bf16 pool ----------------
__global__ __launch_bounds__(256) void conv_w(const float* w0,const float* w1,const float* w2,
                                              const float* w3,const float* w4,const float* w5,
                                              ushort* pool)
{
  size_t idx4 = (size_t)blockIdx.x*256 + threadIdx.x;   // 13,565,952 quads total, grid exact
  size_t e = idx4*4;
  const float* src; size_t base;
  if      (e <  1769472u){src=w0;base=0;}
  else if (e <  2359296u){src=w1;base=1769472u;}
  else if (e <  9437184u){src=w2;base=2359296u;}
  else if (e < 16515072u){src=w3;base=9437184u;}
  else if (e < 35389440u){src=w4;base=16515072u;}
  else                   {src=w5;base=35389440u;}
  f32x4 f = *(const f32x4*)(src + (e-base));
  ushort4 u; u.x=f2b(f[0]); u.y=f2b(f[1]); u.z=f2b(f[2]); u.w=f2b(f[3]);
  *(ushort4*)(pool+e) = u;
}

// ---------------- LayerNorm kernels (wave per token) ----------------
__global__ __launch_bounds__(256) void ln1_k(const float* __restrict__ x, const float* __restrict__ g,
                                             const float* __restrict__ b, ushort* __restrict__ out)
{
  int w = blockIdx.x*4 + (threadIdx.x>>6);
  int lane = threadIdx.x & 63;
  const float* xr = x + (size_t)w*EDIM;
  float v[12]; float s=0.f, s2=0.f;
  #pragma unroll
  for (int i=0;i<12;i++){ v[i]=xr[lane+64*i]; s+=v[i]; s2+=v[i]*v[i]; }
  #pragma unroll
  for (int o=32;o>0;o>>=1){ s += __shfl_xor(s,o); s2 += __shfl_xor(s2,o); }
  float mu = s*(1.f/768.f);
  float rs = rsqrtf(s2*(1.f/768.f) - mu*mu + 1e-5f);
  ushort* op = out + (size_t)w*EDIM;
  #pragma unroll
  for (int i=0;i<12;i++){ int d=lane+64*i; op[d] = f2b((v[i]-mu)*rs*g[d] + b[d]); }
}

// x1 -> z = (LN(x1,g,b) - mu2)/sigma2  (core for per-expert LN folding)
__global__ __launch_bounds__(256) void ln2z_k(const float* __restrict__ x1, const float* __restrict__ g,
                                              const float* __restrict__ b, ushort* __restrict__ z)
{
  int w = blockIdx.x*4 + (threadIdx.x>>6);
  int lane = threadIdx.x & 63;
  const float* xr = x1 + (size_t)w*EDIM;
  float v[12]; float s=0.f, s2=0.f;
  #pragma unroll
  for (int i=0;i<12;i++){ v[i]=xr[lane+64*i]; s+=v[i]; s2+=v[i]*v[i]; }
  #pragma unroll
  for (int o=32;o>0;o>>=1){ s += __shfl_xor(s,o); s2 += __shfl_xor(s2,o); }
  float mu = s*(1.f/768.f);
  float rs = rsqrtf(s2*(1.f/768.f) - mu*mu + 1e-5f);
  float xn[12]; s=0.f; s2=0.f;
  #pragma unroll
  for (int i=0;i<12;i++){ int d=lane+64*i; xn[i]=(v[i]-mu)*rs*g[d]+b[d]; s+=xn[i]; s2+=xn[i]*xn[i]; }
  #pragma unroll
  for (int o=32;o>0;o>>=1){ s += __shfl_xor(s,o); s2 += __shfl_xor(s2,o); }
  float mu2 = s*(1.f/768.f);
  float rs2 = rsqrtf(s2*(1.f/768.f) - mu2*mu2 + 1e-5f);
  ushort* op = z + (size_t)w*EDIM;
  #pragma unroll
  for (int i=0;i<12;i++){ int d=lane+64*i; op[d] = f2b((xn[i]-mu2)*rs2); }
}

// router: recompute LN2 in fp32 (selection matches reference), softmax->top2->softmax -> coef[tok][8]
__global__ __launch_bounds__(256) void router_k(const float* __restrict__ x1, const float* __restrict__ g2,
                                                const float* __restrict__ b2, const float* __restrict__ rw,
                                                const float* __restrict__ rbv, float* __restrict__ coef)
{
  int w = blockIdx.x*4 + (threadIdx.x>>6);
  int lane = threadIdx.x & 63;
  const float* xr = x1 + (size_t)w*EDIM;
  float v[12]; float s=0.f, s2=0.f;
  #pragma unroll
  for (int i=0;i<12;i++){ v[i]=xr[lane+64*i]; s+=v[i]; s2+=v[i]*v[i]; }
  #pragma unroll
  for (int o=32;o>0;o>>=1){ s += __shfl_xor(s,o); s2 += __shfl_xor(s2,o); }
  float mu = s*(1.f/768.f);
  float rs = rsqrtf(s2*(1.f/768.f) - mu*mu + 1e-5f);
  float xn[12];
  #pragma unroll
  for (int i=0;i<12;i++){ int d=lane+64*i; xn[i]=(v[i]-mu)*rs*g2[d]+b2[d]; }
  float pl[8] = {0.f,0.f,0.f,0.f,0.f,0.f,0.f,0.f};
  #pragma unroll
  for (int i=0;i<12;i++){
    int d=lane+64*i; float xv=xn[i];
    #pragma unroll
    for (int e=0;e<8;e++) pl[e] += xv * rw[e*EDIM + d];
  }
  #pragma unroll
  for (int e=0;e<8;e++){
    #pragma unroll
    for (int o=32;o>0;o>>=1) pl[e] += __shfl_xor(pl[e], o);
  }
  float lgt[8]; float mx = -1e30f;
  #pragma unroll
  for (int e=0;e<8;e++){ lgt[e]=pl[e]+rbv[e]; mx = fmaxf(mx, lgt[e]); }
  float p[8]; float den=0.f;
  #pragma unroll
  for (int e=0;e<8;e++){ p[e]=__expf(lgt[e]-mx); den+=p[e]; }
  float inv = 1.f/den;
  #pragma unroll
  for (int e=0;e<8;e++) p[e]*=inv;
  int i1=0;
  #pragma unroll
  for (int e=1;e<8;e++) if (p[e]>p[i1]) i1=e;
  int i2=(i1==0)?1:0;
  #pragma unroll
  for (int e=0;e<8;e++){ if (e==i1) continue; if (p[e]>p[i2]) i2=e; }
  float w1 = 1.f/(1.f+__expf(p[i2]-p[i1]));   // softmax over the two top PROBS
  float w2 = 1.f - w1;
  if (lane < 8){
    float c = (lane==i1)? w1 : ((lane==i2)? w2 : 0.f);
    coef[(size_t)w*8 + lane] = c;
  }
}

// deterministic gather lists via block-wide prefix sums (no atomics)
__global__ __launch_bounds__(256) void build_lists(const int* __restrict__ mt, const float* __restrict__ coef,
                                                   int* __restrict__ lists, int* __restrict__ cnt)
{
  const int job = blockIdx.x;       // 0: mt==0, 1: mt==1, 2..9: general expert job-2
  int* list = lists + (size_t)job*NTOK;
  __shared__ int wsum[4];
  int base = 0;
  const int lane = threadIdx.x & 63, wv = threadIdx.x >> 6;
  for (int c0=0; c0<NTOK; c0+=256){
    int t = c0 + threadIdx.x;
    bool flag;
    if (job==0)      flag = (mt[t]==0);
    else if (job==1) flag = (mt[t]==1);
    else             flag = (coef[(size_t)t*8 + (job-2)] != 0.0f);
    unsigned long long bal = __ballot(flag);
    int pre = __popcll(bal & ((1ull<<lane)-1ull));
    if (lane==0) wsum[wv] = __popcll(bal);
    __syncthreads();
    int off = base + pre;
    for (int k=0;k<wv;k++) off += wsum[k];
    int tot = wsum[0]+wsum[1]+wsum[2]+wsum[3];
    if (flag) list[off] = t;
    base += tot;
    __syncthreads();
  }
  if (threadIdx.x==0) cnt[job+1] = base;
}

// ---------------- MFMA GEMM: C[M,N] = A[M,K] @ B[N,K]^T (+epilogues) ----------------
struct GemmArgs {
  const ushort* A; const ushort* B;
  const float* bias; const float* resid;
  float* outF; ushort* outBF;
  const int* list; const int* cntPtr; const float* coef;
  const float* lg; const float* lb;
  int M, K, ldc, eidx;
};

// EPI: 0 = bias->bf16 ; 1 = bias+resid->f32 ; 2 = bias+GELU->bf16 ; 3 = bias,*coef, += f32 scatter
template<int EPI, int AGATHER, int FOLD>
__global__ __launch_bounds__(256) void gemm_k(GemmArgs g)
{
  const int mb = blockIdx.x, nb = blockIdx.y;
  const int cnt = g.cntPtr ? *g.cntPtr : g.M;
  if (mb*128 >= cnt) return;
  __shared__ __align__(16) ushort As[128*40];
  __shared__ __align__(16) ushort Bs[128*40];
  const int tid = threadIdx.x;
  const int lane = tid & 63, wave = tid >> 6;
  const int ar = tid >> 2, ac = tid & 3;
  const int row0 = mb*128 + ar, row1 = row0 + 64;
  int t0, t1;
  if (AGATHER){ t0 = g.list[min(row0, cnt-1)]; t1 = g.list[min(row1, cnt-1)]; }
  else        { t0 = row0; t1 = row1; }
  const int KK = g.K;
  const ushort* Ap0 = g.A + (size_t)t0*KK + ac*8;
  const ushort* Ap1 = g.A + (size_t)t1*KK + ac*8;
  const ushort* Bp0 = g.B + (size_t)(nb*128+ar)*KK + ac*8;
  const ushort* Bp1 = Bp0 + (size_t)64*KK;
  const int nst = KK >> 5;
  uint4 ra0 = *(const uint4*)(Ap0);
  uint4 ra1 = *(const uint4*)(Ap1);
  uint4 rb0 = *(const uint4*)(Bp0);
  uint4 rb1 = *(const uint4*)(Bp1);
  if (FOLD){ int k0 = ac*8; ra0 = fold8(ra0,g.lg,g.lb,k0); ra1 = fold8(ra1,g.lg,g.lb,k0); }
  f32x4 acc[4][4];
  #pragma unroll
  for (int m=0;m<4;m++)
    #pragma unroll
    for (int n=0;n<4;n++) acc[m][n] = (f32x4){0.f,0.f,0.f,0.f};
  const int fr = lane & 15, fq = lane >> 4;
  const int rb_ = (wave>>1)*64, cb_ = (wave&1)*64;
  for (int kt=0; kt<nst; ++kt){
    __syncthreads();
    *(uint4*)&As[ ar     *40 + ac*8] = ra0;
    *(uint4*)&As[(ar+64) *40 + ac*8] = ra1;
    *(uint4*)&Bs[ ar     *40 + ac*8] = rb0;
    *(uint4*)&Bs[(ar+64) *40 + ac*8] = rb1;
    if (kt+1 < nst){
      const int ko = (kt+1)*32;
      ra0 = *(const uint4*)(Ap0 + ko);
      ra1 = *(const uint4*)(Ap1 + ko);
      rb0 = *(const uint4*)(Bp0 + ko);
      rb1 = *(const uint4*)(Bp1 + ko);
      if (FOLD){ int k0 = ko + ac*8; ra0 = fold8(ra0,g.lg,g.lb,k0); ra1 = fold8(ra1,g.lg,g.lb,k0); }
    }
    __syncthreads();
    bf16x8 af[4], bfr[4];
    #pragma unroll
    for (int m=0;m<4;m++) af[m]  = *(const bf16x8*)&As[(rb_ + m*16 + fr)*40 + fq*8];
    #pragma unroll
    for (int n=0;n<4;n++) bfr[n] = *(const bf16x8*)&Bs[(cb_ + n*16 + fr)*40 + fq*8];
    #pragma unroll
    for (int m=0;m<4;m++)
      #pragma unroll
      for (int n=0;n<4;n++)
        acc[m][n] = __builtin_amdgcn_mfma_f32_16x16x32_bf16(af[m], bfr[n], acc[m][n], 0, 0, 0);
  }
  #pragma unroll
  for (int m=0;m<4;m++){
    #pragma unroll
    for (int j=0;j<4;j++){
      const int row = mb*128 + rb_ + m*16 + fq*4 + j;
      #pragma unroll
      for (int n=0;n<4;n++){
        const int col = nb*128 + cb_ + n*16 + fr;
        float v = acc[m][n][j] + g.bias[col];
        if (EPI==0){
          g.outBF[(size_t)row*g.ldc + col] = f2b(v);
        } else if (EPI==1){
          v += g.resid[(size_t)row*g.ldc + col];
          g.outF[(size_t)row*g.ldc + col] = v;
        } else if (EPI==2){
          g.outBF[(size_t)row*g.ldc + col] = f2b(gelu_f(v));
        } else {
          if (row < cnt){
            const int tok = g.list ? g.list[row] : row;
            const float c = g.coef ? g.coef[(size_t)tok*8 + g.eidx] : 1.0f;
            g.outF[(size_t)tok*g.ldc + col] += c*v;
          }
        }
      }
    }
  }
}

// ---------------- fp32 flash attention (QB=KB=64, 4x4 micro-tiles, swizzled LDS) ----------------
__global__ __launch_bounds__(256) void attn_k(const ushort* __restrict__ qkv, ushort* __restrict__ ctx)
{
  const int qb = blockIdx.x, bh = blockIdx.y;
  const int b = bh/12, h = bh%12;
  const int tid = threadIdx.x;
  __shared__ __align__(16) float Qs[4096];
  __shared__ __align__(16) float KPs[4096];     // K tile, reused as P tile
  __shared__ __align__(16) float Vs[4096];
  __shared__ float rowm[64], rowl[64], rowa[64];
  const int lr = tid>>2, lc = tid&3;
  const size_t q0 = (size_t)b*1024 + (size_t)qb*64;
  #pragma unroll
  for (int i=0;i<4;i++){
    int ch = lc + 4*i;
    const ushort* p = qkv + (q0+lr)*2304 + h*64 + ch*4;
    ushort4 u = *(const ushort4*)p;
    f32x4 f = { b2f(u.x)*0.125f, b2f(u.y)*0.125f, b2f(u.z)*0.125f, b2f(u.w)*0.125f };
    *(f32x4*)&Qs[(lr<<6) + ((ch ^ (lr&15))<<2)] = f;
  }
  if (tid < 64){ rowm[tid] = -1e30f; rowl[tid] = 0.f; }
  float o[4][4] = {};
  const int tr = tid>>4, tc = tid&15;
  for (int kt=0; kt<16; ++kt){
    __syncthreads();                               // A: prev PV done; Q/init visible
    #pragma unroll
    for (int i=0;i<4;i++){
      int ch = lc + 4*i;
      size_t tk = (size_t)b*1024 + (size_t)kt*64 + lr;
      const ushort* pk = qkv + tk*2304 + 768 + h*64 + ch*4;
      ushort4 uk = *(const ushort4*)pk;
      ushort4 uv = *(const ushort4*)(pk + 768);
      f32x4 fk = { b2f(uk.x), b2f(uk.y), b2f(uk.z), b2f(uk.w) };
      f32x4 fv = { b2f(uv.x), b2f(uv.y), b2f(uv.z), b2f(uv.w) };
      int sw = (lr<<6) + ((ch ^ (lr&15))<<2);
      *(f32x4*)&KPs[sw] = fk;
      *(f32x4*)&Vs[sw]  = fv;
    }
    __syncthreads();                               // B: K,V ready
    float sacc[4][4] = {};
    #pragma unroll
    for (int d4=0; d4<16; ++d4){
      f32x4 qv[4], kv[4];
      #pragma unroll
      for (int i=0;i<4;i++){ int r=tr*4+i; qv[i] = *(const f32x4*)&Qs[(r<<6)+((d4^(r&15))<<2)]; }
      #pragma unroll
      for (int j=0;j<4;j++){ int c=tc*4+j; kv[j] = *(const f32x4*)&KPs[(c<<6)+((d4^(c&15))<<2)]; }
      #pragma unroll
      for (int i=0;i<4;i++)
        #pragma unroll
        for (int j=0;j<4;j++)
          sacc[i][j] += qv[i][0]*kv[j][0] + qv[i][1]*kv[j][1] + qv[i][2]*kv[j][2] + qv[i][3]*kv[j][3];
    }
    __syncthreads();                               // C: done reading K; KPs becomes P
    #pragma unroll
    for (int i=0;i<4;i++){
      int r = tr*4+i;
      f32x4 sv = { sacc[i][0], sacc[i][1], sacc[i][2], sacc[i][3] };
      *(f32x4*)&KPs[(r<<6)+((tc^(r&15))<<2)] = sv;
    }
    __syncthreads();                               // D: P written
    {
      const int r = tid>>2, part = tid&3;
      float mloc = -1e30f;
      #pragma unroll
      for (int c4=0;c4<4;c4++){
        f32x4 pv = *(const f32x4*)&KPs[(r<<6)+(((part*4+c4)^(r&15))<<2)];
        mloc = fmaxf(mloc, fmaxf(fmaxf(pv[0],pv[1]), fmaxf(pv[2],pv[3])));
      }
      mloc = fmaxf(mloc, __shfl_xor(mloc,1));
      mloc = fmaxf(mloc, __shfl_xor(mloc,2));
      float mold = rowm[r];
      float mnew = fmaxf(mold, mloc);
      float ss = 0.f;
      #pragma unroll
      for (int c4=0;c4<4;c4++){
        int idx = (r<<6)+(((part*4+c4)^(r&15))<<2);
        f32x4 pv = *(const f32x4*)&KPs[idx];
        pv[0]=__expf(pv[0]-mnew); pv[1]=__expf(pv[1]-mnew); pv[2]=__expf(pv[2]-mnew); pv[3]=__expf(pv[3]-mnew);
        ss += pv[0]+pv[1]+pv[2]+pv[3];
        *(f32x4*)&KPs[idx] = pv;
      }
      ss += __shfl_xor(ss,1);
      ss += __shfl_xor(ss,2);
      if (part==0){
        float al = __expf(mold - mnew);
        rowa[r] = al;
        rowl[r] = rowl[r]*al + ss;
        rowm[r] = mnew;
      }
    }
    __syncthreads();                               // E: P exp'd + stats ready
    #pragma unroll
    for (int i=0;i<4;i++){
      float al = rowa[tr*4+i];
      #pragma unroll
      for (int j=0;j<4;j++) o[i][j] *= al;
    }
    #pragma unroll
    for (int k4=0;k4<16;k4++){
      f32x4 vv[4];
      #pragma unroll
      for (int kk=0;kk<4;kk++){ int kr=k4*4+kk; vv[kk] = *(const f32x4*)&Vs[(kr<<6)+((tc^(kr&15))<<2)]; }
      #pragma unroll
      for (int i=0;i<4;i++){
        int r=tr*4+i;
        f32x4 pv = *(const f32x4*)&KPs[(r<<6)+((k4^(r&15))<<2)];
        #pragma unroll
        for (int j=0;j<4;j++)
          o[i][j] += pv[0]*vv[0][j] + pv[1]*vv[1][j] + pv[2]*vv[2][j] + pv[3]*vv[3][j];
      }
    }
  }
  #pragma unroll
  for (int i=0;i<4;i++){
    int r = tr*4+i;
    float inv = 1.f/rowl[r];
    ushort4 u;
    u.x = f2b(o[i][0]*inv); u.y = f2b(o[i][1]*inv); u.z = f2b(o[i][2]*inv); u.w = f2b(o[i][3]*inv);
    *(ushort4*)(ctx + (q0+r)*768 + h*64 + tc*4) = u;
  }
}

extern "C" void kernel_launch(void* const* d_in, const int* in_sizes, int n_in,
                              void* d_out, int out_size, void* d_ws, size_t ws_size,
                              hipStream_t stream)
{
  const float* x    = (const float*)d_in[0];
  const int*   mt   = (const int*)d_in[1];
  const float* n1g  = (const float*)d_in[2];
  const float* n1b  = (const float*)d_in[3];
  const float* n2g  = (const float*)d_in[4];
  const float* n2b  = (const float*)d_in[5];
  const float* wqkv = (const float*)d_in[6];
  const float* bqkv = (const float*)d_in[7];
  const float* wo   = (const float*)d_in[8];
  const float* bo   = (const float*)d_in[9];
  const float* rw   = (const float*)d_in[10];
  const float* rb   = (const float*)d_in[11];
  const float* slg  = (const float*)d_in[12];
  const float* slb  = (const float*)d_in[13];
  const float* sw1  = (const float*)d_in[14];
  const float* sb1  = (const float*)d_in[15];
  const float* sw2  = (const float*)d_in[16];
  const float* sb2  = (const float*)d_in[17];
  const float* glg  = (const float*)d_in[18];
  const float* glb  = (const float*)d_in[19];
  const float* gw1  = (const float*)d_in[20];
  const float* gb1  = (const float*)d_in[21];
  const float* gw2  = (const float*)d_in[22];
  const float* gb2  = (const float*)d_in[23];
  float* out = (float*)d_out;   // fp32 output == post-attn residual + expert accumulation
  char* ws = (char*)d_ws;

  ushort* pool  = (ushort*)(ws + 0);
  ushort* z     = (ushort*)(ws + 108527616);
  ushort* qkv   = (ushort*)(ws + 121110528);
  ushort* ctx   = (ushort*)(ws + 158859264);
  ushort* xn1   = (ushort*)(ws + 171442176);
  float*  coef  = (float*) (ws + 184025088);
  int*    lists = (int*)   (ws + 184287232);
  int*    cnt   = (int*)   (ws + 184614912);
  ushort* hbuf  = qkv;                        // reuse qkv+ctx region (exactly N*F bf16) as FFN hidden

  ushort* pWqkv = pool + 0;
  ushort* pWo   = pool + 1769472;
  ushort* pSw1  = pool + 2359296;
  ushort* pSw2  = pool + 9437184;
  ushort* pGw1  = pool + 16515072;
  ushort* pGw2  = pool + 35389440;

  conv_w<<<52992, 256, 0, stream>>>(wqkv, wo, sw1, sw2, gw1, gw2, pool);
  ln1_k<<<2048, 256, 0, stream>>>(x, n1g, n1b, xn1);
  { GemmArgs a{}; a.A=xn1; a.B=pWqkv; a.bias=bqkv; a.outBF=qkv; a.M=NTOK; a.K=768; a.ldc=2304;
    gemm_k<0,0,0><<<dim3(64,18),256,0,stream>>>(a); }
  attn_k<<<dim3(16,96),256,0,stream>>>(qkv, ctx);
  { GemmArgs a{}; a.A=ctx; a.B=pWo; a.bias=bo; a.resid=x; a.outF=out; a.M=NTOK; a.K=768; a.ldc=768;
    gemm_k<1,0,0><<<dim3(64,6),256,0,stream>>>(a); }
  ln2z_k<<<2048,256,0,stream>>>(out, n2g, n2b, z);
  router_k<<<2048,256,0,stream>>>(out, n2g, n2b, rw, rb, coef);
  build_lists<<<10,256,0,stream>>>(mt, coef, lists, cnt);

  for (int j=0;j<11;j++){
    const int* list = (j==0)? nullptr : lists + (size_t)(j-1)*NTOK;
    const int* cp   = (j==0)? nullptr : cnt + j;
    const float* lgp = (j<3)? slg + (size_t)j*EDIM : glg + (size_t)(j-3)*EDIM;
    const float* lbp = (j<3)? slb + (size_t)j*EDIM : glb + (size_t)(j-3)*EDIM;
    const ushort* w1 = (j<3)? pSw1 + (size_t)j*FDIM*EDIM : pGw1 + (size_t)(j-3)*FDIM*EDIM;
    const float*  b1 = (j<3)? sb1 + (size_t)j*FDIM : gb1 + (size_t)(j-3)*FDIM;
    const ushort* w2 = (j<3)? pSw2 + (size_t)j*EDIM*FDIM : pGw2 + (size_t)(j-3)*EDIM*FDIM;
    const float*  b2 = (j<3)? sb2 + (size_t)j*EDIM : gb2 + (size_t)(j-3)*EDIM;
    { GemmArgs a{}; a.A=z; a.B=w1; a.bias=b1; a.outBF=hbuf; a.list=list; a.cntPtr=cp;
      a.lg=lgp; a.lb=lbp; a.M=NTOK; a.K=768; a.ldc=3072;
      if (j==0) gemm_k<2,0,1><<<dim3(64,24),256,0,stream>>>(a);
      else      gemm_k<2,1,1><<<dim3(64,24),256,0,stream>>>(a); }
    { GemmArgs a{}; a.A=hbuf; a.B=w2; a.bias=b2; a.outF=out; a.list=list; a.cntPtr=cp;
      a.coef=(j>=3)? coef : nullptr; a.eidx=j-3; a.M=NTOK; a.K=3072; a.ldc=768;
      gemm_k<3,0,0><<<dim3(64,6),256,0,stream>>>(a); }
  }
}

// Round 3
// 1840.738 us; speedup vs baseline: 1.3512x; 1.3512x over previous
//
#include <hip/hip_runtime.h>
#include <cstdint>

#define NTOK 8192
#define EDIM 768
#define FDIM 3072

using bf16x8 = __attribute__((ext_vector_type(8))) __bf16;
using f32x4  = __attribute__((ext_vector_type(4))) float;

__device__ __forceinline__ float b2f(ushort u){ union{uint32_t i; float f;} v; v.i = ((uint32_t)u)<<16; return v.f; }
__device__ __forceinline__ ushort f2b(float f){ union{float f; uint32_t i;} v; v.f=f; uint32_t r = v.i + 0x7fffu + ((v.i>>16)&1u); return (ushort)(r>>16); }
__device__ __forceinline__ float gelu_f(float v){ return 0.5f*v*(1.0f+erff(v*0.70710678118654752f)); }

__device__ __forceinline__ uint4 fold8(uint4 v, const float* gl, const float* bl, int k){
  union { uint4 q; ushort s[8]; } u; u.q = v;
  f32x4 g0 = *(const f32x4*)(gl+k);
  f32x4 g1 = *(const f32x4*)(gl+k+4);
  f32x4 b0 = *(const f32x4*)(bl+k);
  f32x4 b1 = *(const f32x4*)(bl+k+4);
  #pragma unroll
  for (int i=0;i<4;i++) u.s[i]   = f2b(b2f(u.s[i])  *g0[i] + b0[i]);
  #pragma unroll
  for (int i=0;i<4;i++) u.s[4+i] = f2b(b2f(u.s[4+i])*g1[i] + b1[i]);
  return u.q;
}

// ---------------- weight fp32 -> bf16 pool ----------------
__global__ __launch_bounds__(256) void conv_w(const float* w0,const float* w1,const float* w2,
                                              const float* w3,const float* w4,const float* w5,
                                              ushort* pool)
{
  size_t idx4 = (size_t)blockIdx.x*256 + threadIdx.x;   // 13,565,952 quads total, grid exact
  size_t e = idx4*4;
  const float* src; size_t base;
  if      (e <  1769472u){src=w0;base=0;}
  else if (e <  2359296u){src=w1;base=1769472u;}
  else if (e <  9437184u){src=w2;base=2359296u;}
  else if (e < 16515072u){src=w3;base=9437184u;}
  else if (e < 35389440u){src=w4;base=16515072u;}
  else                   {src=w5;base=35389440u;}
  f32x4 f = *(const f32x4*)(src + (e-base));
  ushort4 u; u.x=f2b(f[0]); u.y=f2b(f[1]); u.z=f2b(f[2]); u.w=f2b(f[3]);
  *(ushort4*)(pool+e) = u;
}

// ---------------- LayerNorm kernels (wave per token) ----------------
__global__ __launch_bounds__(256) void ln1_k(const float* __restrict__ x, const float* __restrict__ g,
                                             const float* __restrict__ b, ushort* __restrict__ out)
{
  int w = blockIdx.x*4 + (threadIdx.x>>6);
  int lane = threadIdx.x & 63;
  const float* xr = x + (size_t)w*EDIM;
  float v[12]; float s=0.f, s2=0.f;
  #pragma unroll
  for (int i=0;i<12;i++){ v[i]=xr[lane+64*i]; s+=v[i]; s2+=v[i]*v[i]; }
  #pragma unroll
  for (int o=32;o>0;o>>=1){ s += __shfl_xor(s,o); s2 += __shfl_xor(s2,o); }
  float mu = s*(1.f/768.f);
  float rs = rsqrtf(s2*(1.f/768.f) - mu*mu + 1e-5f);
  ushort* op = out + (size_t)w*EDIM;
  #pragma unroll
  for (int i=0;i<12;i++){ int d=lane+64*i; op[d] = f2b((v[i]-mu)*rs*g[d] + b[d]); }
}

// x1 -> z = (LN(x1,g,b) - mu2)/sigma2  (core for per-expert LN folding)
__global__ __launch_bounds__(256) void ln2z_k(const float* __restrict__ x1, const float* __restrict__ g,
                                              const float* __restrict__ b, ushort* __restrict__ z)
{
  int w = blockIdx.x*4 + (threadIdx.x>>6);
  int lane = threadIdx.x & 63;
  const float* xr = x1 + (size_t)w*EDIM;
  float v[12]; float s=0.f, s2=0.f;
  #pragma unroll
  for (int i=0;i<12;i++){ v[i]=xr[lane+64*i]; s+=v[i]; s2+=v[i]*v[i]; }
  #pragma unroll
  for (int o=32;o>0;o>>=1){ s += __shfl_xor(s,o); s2 += __shfl_xor(s2,o); }
  float mu = s*(1.f/768.f);
  float rs = rsqrtf(s2*(1.f/768.f) - mu*mu + 1e-5f);
  float xn[12]; s=0.f; s2=0.f;
  #pragma unroll
  for (int i=0;i<12;i++){ int d=lane+64*i; xn[i]=(v[i]-mu)*rs*g[d]+b[d]; s+=xn[i]; s2+=xn[i]*xn[i]; }
  #pragma unroll
  for (int o=32;o>0;o>>=1){ s += __shfl_xor(s,o); s2 += __shfl_xor(s2,o); }
  float mu2 = s*(1.f/768.f);
  float rs2 = rsqrtf(s2*(1.f/768.f) - mu2*mu2 + 1e-5f);
  ushort* op = z + (size_t)w*EDIM;
  #pragma unroll
  for (int i=0;i<12;i++){ int d=lane+64*i; op[d] = f2b((xn[i]-mu2)*rs2); }
}

// router: recompute LN2 in fp32 (selection matches reference), softmax->top2->softmax -> coef[tok][8]
__global__ __launch_bounds__(256) void router_k(const float* __restrict__ x1, const float* __restrict__ g2,
                                                const float* __restrict__ b2, const float* __restrict__ rw,
                                                const float* __restrict__ rbv, float* __restrict__ coef)
{
  int w = blockIdx.x*4 + (threadIdx.x>>6);
  int lane = threadIdx.x & 63;
  const float* xr = x1 + (size_t)w*EDIM;
  float v[12]; float s=0.f, s2=0.f;
  #pragma unroll
  for (int i=0;i<12;i++){ v[i]=xr[lane+64*i]; s+=v[i]; s2+=v[i]*v[i]; }
  #pragma unroll
  for (int o=32;o>0;o>>=1){ s += __shfl_xor(s,o); s2 += __shfl_xor(s2,o); }
  float mu = s*(1.f/768.f);
  float rs = rsqrtf(s2*(1.f/768.f) - mu*mu + 1e-5f);
  float xn[12];
  #pragma unroll
  for (int i=0;i<12;i++){ int d=lane+64*i; xn[i]=(v[i]-mu)*rs*g2[d]+b2[d]; }
  float pl[8] = {0.f,0.f,0.f,0.f,0.f,0.f,0.f,0.f};
  #pragma unroll
  for (int i=0;i<12;i++){
    int d=lane+64*i; float xv=xn[i];
    #pragma unroll
    for (int e=0;e<8;e++) pl[e] += xv * rw[e*EDIM + d];
  }
  #pragma unroll
  for (int e=0;e<8;e++){
    #pragma unroll
    for (int o=32;o>0;o>>=1) pl[e] += __shfl_xor(pl[e], o);
  }
  float lgt[8]; float mx = -1e30f;
  #pragma unroll
  for (int e=0;e<8;e++){ lgt[e]=pl[e]+rbv[e]; mx = fmaxf(mx, lgt[e]); }
  float p[8]; float den=0.f;
  #pragma unroll
  for (int e=0;e<8;e++){ p[e]=__expf(lgt[e]-mx); den+=p[e]; }
  float inv = 1.f/den;
  #pragma unroll
  for (int e=0;e<8;e++) p[e]*=inv;
  int i1=0;
  #pragma unroll
  for (int e=1;e<8;e++) if (p[e]>p[i1]) i1=e;
  int i2=(i1==0)?1:0;
  #pragma unroll
  for (int e=0;e<8;e++){ if (e==i1) continue; if (p[e]>p[i2]) i2=e; }
  float w1 = 1.f/(1.f+__expf(p[i2]-p[i1]));   // softmax over the two top PROBS
  float w2 = 1.f - w1;
  if (lane < 8){
    float c = (lane==i1)? w1 : ((lane==i2)? w2 : 0.f);
    coef[(size_t)w*8 + lane] = c;
  }
}

// deterministic gather lists via block-wide prefix sums (no atomics)
__global__ __launch_bounds__(256) void build_lists(const int* __restrict__ mt, const float* __restrict__ coef,
                                                   int* __restrict__ lists, int* __restrict__ cnt)
{
  const int job = blockIdx.x;       // 0: mt==0, 1: mt==1, 2..9: general expert job-2
  int* list = lists + (size_t)job*NTOK;
  __shared__ int wsum[4];
  int base = 0;
  const int lane = threadIdx.x & 63, wv = threadIdx.x >> 6;
  for (int c0=0; c0<NTOK; c0+=256){
    int t = c0 + threadIdx.x;
    bool flag;
    if (job==0)      flag = (mt[t]==0);
    else if (job==1) flag = (mt[t]==1);
    else             flag = (coef[(size_t)t*8 + (job-2)] != 0.0f);
    unsigned long long bal = __ballot(flag);
    int pre = __popcll(bal & ((1ull<<lane)-1ull));
    if (lane==0) wsum[wv] = __popcll(bal);
    __syncthreads();
    int off = base + pre;
    for (int k=0;k<wv;k++) off += wsum[k];
    int tot = wsum[0]+wsum[1]+wsum[2]+wsum[3];
    if (flag) list[off] = t;
    base += tot;
    __syncthreads();
  }
  if (threadIdx.x==0) cnt[job+1] = base;
}

// ---------------- MFMA GEMM: C[M,N] = A[M,K] @ B[N,K]^T (+epilogues) ----------------
struct GemmArgs {
  const ushort* A; const ushort* B;
  const float* bias; const float* resid;
  float* outF; ushort* outBF;
  const int* list; const int* cntPtr; const float* coef;
  const float* lg; const float* lb;
  int M, K, ldc, eidx;
};

// EPI: 0 = bias->bf16 ; 1 = bias+resid->f32 ; 2 = bias+GELU->bf16 ; 3 = bias,*coef, += f32 scatter
template<int EPI, int AGATHER, int FOLD>
__global__ __launch_bounds__(256) void gemm_k(GemmArgs g)
{
  const int mb = blockIdx.x, nb = blockIdx.y;
  const int cnt = g.cntPtr ? *g.cntPtr : g.M;
  if (mb*128 >= cnt) return;
  __shared__ __align__(16) ushort As[128*40];
  __shared__ __align__(16) ushort Bs[128*40];
  const int tid = threadIdx.x;
  const int lane = tid & 63, wave = tid >> 6;
  const int ar = tid >> 2, ac = tid & 3;
  const int row0 = mb*128 + ar, row1 = row0 + 64;
  int t0, t1;
  if (AGATHER){ t0 = g.list[min(row0, cnt-1)]; t1 = g.list[min(row1, cnt-1)]; }
  else        { t0 = row0; t1 = row1; }
  const int KK = g.K;
  const ushort* Ap0 = g.A + (size_t)t0*KK + ac*8;
  const ushort* Ap1 = g.A + (size_t)t1*KK + ac*8;
  const ushort* Bp0 = g.B + (size_t)(nb*128+ar)*KK + ac*8;
  const ushort* Bp1 = Bp0 + (size_t)64*KK;
  const int nst = KK >> 5;
  uint4 ra0 = *(const uint4*)(Ap0);
  uint4 ra1 = *(const uint4*)(Ap1);
  uint4 rb0 = *(const uint4*)(Bp0);
  uint4 rb1 = *(const uint4*)(Bp1);
  if (FOLD){ int k0 = ac*8; ra0 = fold8(ra0,g.lg,g.lb,k0); ra1 = fold8(ra1,g.lg,g.lb,k0); }
  f32x4 acc[4][4];
  #pragma unroll
  for (int m=0;m<4;m++)
    #pragma unroll
    for (int n=0;n<4;n++) acc[m][n] = (f32x4){0.f,0.f,0.f,0.f};
  const int fr = lane & 15, fq = lane >> 4;
  const int rb_ = (wave>>1)*64, cb_ = (wave&1)*64;
  for (int kt=0; kt<nst; ++kt){
    __syncthreads();
    *(uint4*)&As[ ar     *40 + ac*8] = ra0;
    *(uint4*)&As[(ar+64) *40 + ac*8] = ra1;
    *(uint4*)&Bs[ ar     *40 + ac*8] = rb0;
    *(uint4*)&Bs[(ar+64) *40 + ac*8] = rb1;
    if (kt+1 < nst){
      const int ko = (kt+1)*32;
      ra0 = *(const uint4*)(Ap0 + ko);
      ra1 = *(const uint4*)(Ap1 + ko);
      rb0 = *(const uint4*)(Bp0 + ko);
      rb1 = *(const uint4*)(Bp1 + ko);
      if (FOLD){ int k0 = ko + ac*8; ra0 = fold8(ra0,g.lg,g.lb,k0); ra1 = fold8(ra1,g.lg,g.lb,k0); }
    }
    __syncthreads();
    bf16x8 af[4], bfr[4];
    #pragma unroll
    for (int m=0;m<4;m++) af[m]  = *(const bf16x8*)&As[(rb_ + m*16 + fr)*40 + fq*8];
    #pragma unroll
    for (int n=0;n<4;n++) bfr[n] = *(const bf16x8*)&Bs[(cb_ + n*16 + fr)*40 + fq*8];
    #pragma unroll
    for (int m=0;m<4;m++)
      #pragma unroll
      for (int n=0;n<4;n++)
        acc[m][n] = __builtin_amdgcn_mfma_f32_16x16x32_bf16(af[m], bfr[n], acc[m][n], 0, 0, 0);
  }
  #pragma unroll
  for (int m=0;m<4;m++){
    #pragma unroll
    for (int j=0;j<4;j++){
      const int row = mb*128 + rb_ + m*16 + fq*4 + j;
      #pragma unroll
      for (int n=0;n<4;n++){
        const int col = nb*128 + cb_ + n*16 + fr;
        float v = acc[m][n][j] + g.bias[col];
        if (EPI==0){
          g.outBF[(size_t)row*g.ldc + col] = f2b(v);
        } else if (EPI==1){
          v += g.resid[(size_t)row*g.ldc + col];
          g.outF[(size_t)row*g.ldc + col] = v;
        } else if (EPI==2){
          g.outBF[(size_t)row*g.ldc + col] = f2b(gelu_f(v));
        } else {
          if (row < cnt){
            const int tok = g.list ? g.list[row] : row;
            const float c = g.coef ? g.coef[(size_t)tok*8 + g.eidx] : 1.0f;
            g.outF[(size_t)tok*g.ldc + col] += c*v;
          }
        }
      }
    }
  }
}

// ---------------- MFMA flash attention ----------------
// grid (16 qtiles, 96 bh), 256 thr = 4 waves; wave w owns q-rows qb*64 + w*16 .. +15.
// K tile LDS row-major [kv64][d64] bf16, XOR-swizzled (ushort idx: col ^ ((row&7)<<3)).
// V tile stored transposed Vt[d64][kv64], same swizzle. P per-wave [16][64], same swizzle.
__global__ __launch_bounds__(256) void attn_k(const ushort* __restrict__ qkv, ushort* __restrict__ ctx)
{
  const int qb = blockIdx.x, bh = blockIdx.y;
  const int b = bh/12, h = bh%12;
  const int tid = threadIdx.x;
  const int lane = tid & 63, w = tid >> 6;
  const int fr = lane & 15, fq = lane >> 4;
  __shared__ __align__(16) ushort Ks[4096];
  __shared__ __align__(16) ushort Vts[4096];
  __shared__ __align__(16) ushort Ps[4096];
  const size_t tokq = (size_t)b*1024 + (size_t)qb*64;

  // Q fragments (A-frag): lane holds Q[row=w*16+fr][k=fq*8 + ks*32 .. +7]
  bf16x8 qf[2];
  {
    const ushort* qp = qkv + (tokq + w*16 + fr)*2304 + h*64 + fq*8;
    qf[0] = *(const bf16x8*)(qp);
    qf[1] = *(const bf16x8*)(qp + 32);
  }
  f32x4 o[4];
  #pragma unroll
  for (int nt=0;nt<4;nt++) o[nt] = (f32x4){0.f,0.f,0.f,0.f};
  float m[4] = {-1e30f,-1e30f,-1e30f,-1e30f};
  float l[4] = {0.f,0.f,0.f,0.f};

  const int skr = tid>>3, skc = (tid&7)*8;    // K staging coords
  const int svd = (tid&15)*4, svk = (tid>>4)*4; // V staging coords

  for (int kt=0; kt<16; ++kt){
    __syncthreads();                           // all waves done reading Ks/Vts of prev tile
    const size_t tokk = (size_t)b*1024 + (size_t)kt*64;
    // stage K: 2 passes of 16B per thread
    #pragma unroll
    for (int p=0;p<2;p++){
      int row = skr + p*32;
      uint4 kq = *(const uint4*)(qkv + (tokk+row)*2304 + 768 + h*64 + skc);
      *(uint4*)&Ks[row*64 + (skc ^ ((row&7)<<3))] = kq;
    }
    // stage V transposed: 4x4 in-register transpose
    {
      union { ushort4 v4[4]; ushort s[16]; } tv;
      #pragma unroll
      for (int i=0;i<4;i++)
        tv.v4[i] = *(const ushort4*)(qkv + (tokk+svk+i)*2304 + 1536 + h*64 + svd);
      #pragma unroll
      for (int j=0;j<4;j++){
        ushort4 tj; tj.x=tv.s[j]; tj.y=tv.s[4+j]; tj.z=tv.s[8+j]; tj.w=tv.s[12+j];
        int dr = svd + j;
        *(ushort4*)&Vts[dr*64 + (svk ^ ((dr&7)<<3))] = tj;
      }
    }
    __syncthreads();                           // Ks/Vts ready
    // QK^T: S[16q x 64kv] per wave
    f32x4 s[4];
    #pragma unroll
    for (int nt=0;nt<4;nt++){
      s[nt] = (f32x4){0.f,0.f,0.f,0.f};
      int kr = nt*16 + fr;
      const ushort* kb = &Ks[kr*64];
      int sw = (kr&7)<<3;
      bf16x8 k0 = *(const bf16x8*)&kb[(fq*8) ^ sw];
      bf16x8 k1 = *(const bf16x8*)&kb[(fq*8+32) ^ sw];
      s[nt] = __builtin_amdgcn_mfma_f32_16x16x32_bf16(qf[0], k0, s[nt], 0,0,0);
      s[nt] = __builtin_amdgcn_mfma_f32_16x16x32_bf16(qf[1], k1, s[nt], 0,0,0);
    }
    // online softmax on C layout (row=(fq*4+j), col=nt*16+fr); scale 0.125
    float a_[4], pr[4][4];
    #pragma unroll
    for (int j=0;j<4;j++){
      float mx = fmaxf(fmaxf(s[0][j],s[1][j]), fmaxf(s[2][j],s[3][j])) * 0.125f;
      mx = fmaxf(mx, __shfl_xor(mx,1));
      mx = fmaxf(mx, __shfl_xor(mx,2));
      mx = fmaxf(mx, __shfl_xor(mx,4));
      mx = fmaxf(mx, __shfl_xor(mx,8));
      float mn = fmaxf(m[j], mx);
      float a = __expf(m[j] - mn);
      m[j] = mn; a_[j] = a;
      float ss = 0.f;
      #pragma unroll
      for (int nt=0;nt<4;nt++){
        float p = __expf(s[nt][j]*0.125f - mn);
        pr[nt][j] = p; ss += p;
      }
      ss += __shfl_xor(ss,1);
      ss += __shfl_xor(ss,2);
      ss += __shfl_xor(ss,4);
      ss += __shfl_xor(ss,8);
      l[j] = l[j]*a + ss;
    }
    // write P (own wave region) + rescale O
    #pragma unroll
    for (int nt=0;nt<4;nt++){
      #pragma unroll
      for (int j=0;j<4;j++){
        int row = fq*4 + j;
        Ps[w*1024 + row*64 + ((nt*16+fr) ^ ((row&7)<<3))] = f2b(pr[nt][j]);
        o[nt][j] *= a_[j];
      }
    }
    // PV: O[16q x 64d] += P[16 x 64kv] @ V[64kv x 64d]
    #pragma unroll
    for (int ks=0; ks<2; ++ks){
      int kvo = ks*32 + fq*8;
      bf16x8 pf = *(const bf16x8*)&Ps[w*1024 + fr*64 + (kvo ^ ((fr&7)<<3))];
      #pragma unroll
      for (int nt=0;nt<4;nt++){
        int dr = nt*16 + fr;
        bf16x8 vf = *(const bf16x8*)&Vts[dr*64 + (kvo ^ ((dr&7)<<3))];
        o[nt] = __builtin_amdgcn_mfma_f32_16x16x32_bf16(pf, vf, o[nt], 0,0,0);
      }
    }
  }
  // epilogue
  float inv[4];
  #pragma unroll
  for (int j=0;j<4;j++) inv[j] = 1.f/l[j];
  ushort* cp = ctx + (tokq + w*16)*768 + h*64;
  #pragma unroll
  for (int nt=0;nt<4;nt++){
    #pragma unroll
    for (int j=0;j<4;j++){
      cp[(size_t)(fq*4+j)*768 + nt*16 + fr] = f2b(o[nt][j]*inv[j]);
    }
  }
}

extern "C" void kernel_launch(void* const* d_in, const int* in_sizes, int n_in,
                              void* d_out, int out_size, void* d_ws, size_t ws_size,
                              hipStream_t stream)
{
  const float* x    = (const float*)d_in[0];
  const int*   mt   = (const int*)d_in[1];
  const float* n1g  = (const float*)d_in[2];
  const float* n1b  = (const float*)d_in[3];
  const float* n2g  = (const float*)d_in[4];
  const float* n2b  = (const float*)d_in[5];
  const float* wqkv = (const float*)d_in[6];
  const float* bqkv = (const float*)d_in[7];
  const float* wo   = (const float*)d_in[8];
  const float* bo   = (const float*)d_in[9];
  const float* rw   = (const float*)d_in[10];
  const float* rb   = (const float*)d_in[11];
  const float* slg  = (const float*)d_in[12];
  const float* slb  = (const float*)d_in[13];
  const float* sw1  = (const float*)d_in[14];
  const float* sb1  = (const float*)d_in[15];
  const float* sw2  = (const float*)d_in[16];
  const float* sb2  = (const float*)d_in[17];
  const float* glg  = (const float*)d_in[18];
  const float* glb  = (const float*)d_in[19];
  const float* gw1  = (const float*)d_in[20];
  const float* gb1  = (const float*)d_in[21];
  const float* gw2  = (const float*)d_in[22];
  const float* gb2  = (const float*)d_in[23];
  float* out = (float*)d_out;   // fp32 output == post-attn residual + expert accumulation
  char* ws = (char*)d_ws;

  ushort* pool  = (ushort*)(ws + 0);
  ushort* z     = (ushort*)(ws + 108527616);
  ushort* qkv   = (ushort*)(ws + 121110528);
  ushort* ctx   = (ushort*)(ws + 158859264);
  ushort* xn1   = (ushort*)(ws + 171442176);
  float*  coef  = (float*) (ws + 184025088);
  int*    lists = (int*)   (ws + 184287232);
  int*    cnt   = (int*)   (ws + 184614912);
  ushort* hbuf  = qkv;                        // reuse qkv+ctx region (exactly N*F bf16) as FFN hidden

  ushort* pWqkv = pool + 0;
  ushort* pWo   = pool + 1769472;
  ushort* pSw1  = pool + 2359296;
  ushort* pSw2  = pool + 9437184;
  ushort* pGw1  = pool + 16515072;
  ushort* pGw2  = pool + 35389440;

  conv_w<<<52992, 256, 0, stream>>>(wqkv, wo, sw1, sw2, gw1, gw2, pool);
  ln1_k<<<2048, 256, 0, stream>>>(x, n1g, n1b, xn1);
  { GemmArgs a{}; a.A=xn1; a.B=pWqkv; a.bias=bqkv; a.outBF=qkv; a.M=NTOK; a.K=768; a.ldc=2304;
    gemm_k<0,0,0><<<dim3(64,18),256,0,stream>>>(a); }
  attn_k<<<dim3(16,96),256,0,stream>>>(qkv, ctx);
  { GemmArgs a{}; a.A=ctx; a.B=pWo; a.bias=bo; a.resid=x; a.outF=out; a.M=NTOK; a.K=768; a.ldc=768;
    gemm_k<1,0,0><<<dim3(64,6),256,0,stream>>>(a); }
  ln2z_k<<<2048,256,0,stream>>>(out, n2g, n2b, z);
  router_k<<<2048,256,0,stream>>>(out, n2g, n2b, rw, rb, coef);
  build_lists<<<10,256,0,stream>>>(mt, coef, lists, cnt);

  for (int j=0;j<11;j++){
    const int* list = (j==0)? nullptr : lists + (size_t)(j-1)*NTOK;
    const int* cp   = (j==0)? nullptr : cnt + j;
    const float* lgp = (j<3)? slg + (size_t)j*EDIM : glg + (size_t)(j-3)*EDIM;
    const float* lbp = (j<3)? slb + (size_t)j*EDIM : glb + (size_t)(j-3)*EDIM;
    const ushort* w1 = (j<3)? pSw1 + (size_t)j*FDIM*EDIM : pGw1 + (size_t)(j-3)*FDIM*EDIM;
    const float*  b1 = (j<3)? sb1 + (size_t)j*FDIM : gb1 + (size_t)(j-3)*FDIM;
    const ushort* w2 = (j<3)? pSw2 + (size_t)j*EDIM*FDIM : pGw2 + (size_t)(j-3)*EDIM*FDIM;
    const float*  b2 = (j<3)? sb2 + (size_t)j*EDIM : gb2 + (size_t)(j-3)*EDIM;
    { GemmArgs a{}; a.A=z; a.B=w1; a.bias=b1; a.outBF=hbuf; a.list=list; a.cntPtr=cp;
      a.lg=lgp; a.lb=lbp; a.M=NTOK; a.K=768; a.ldc=3072;
      if (j==0) gemm_k<2,0,1><<<dim3(64,24),256,0,stream>>>(a);
      else      gemm_k<2,1,1><<<dim3(64,24),256,0,stream>>>(a); }
    { GemmArgs a{}; a.A=hbuf; a.B=w2; a.bias=b2; a.outF=out; a.list=list; a.cntPtr=cp;
      a.coef=(j>=3)? coef : nullptr; a.eidx=j-3; a.M=NTOK; a.K=3072; a.ldc=768;
      gemm_k<3,0,0><<<dim3(64,6),256,0,stream>>>(a); }
  }
}

// Round 4
// 1333.883 us; speedup vs baseline: 1.8647x; 1.3800x over previous
//
#include <hip/hip_runtime.h>
#include <cstdint>

#define NTOK 8192
#define EDIM 768
#define FDIM 3072

using bf16x8 = __attribute__((ext_vector_type(8))) __bf16;
using f32x4  = __attribute__((ext_vector_type(4))) float;

__device__ __forceinline__ float b2f(ushort u){ union{uint32_t i; float f;} v; v.i = ((uint32_t)u)<<16; return v.f; }
__device__ __forceinline__ ushort f2b(float f){ union{float f; uint32_t i;} v; v.f=f; uint32_t r = v.i + 0x7fffu + ((v.i>>16)&1u); return (ushort)(r>>16); }
__device__ __forceinline__ float gelu_f(float v){ return 0.5f*v*(1.0f+erff(v*0.70710678118654752f)); }

__device__ __forceinline__ uint4 fold8(uint4 v, const float* gl, const float* bl, int k){
  union { uint4 q; ushort s[8]; } u; u.q = v;
  f32x4 g0 = *(const f32x4*)(gl+k);
  f32x4 g1 = *(const f32x4*)(gl+k+4);
  f32x4 b0 = *(const f32x4*)(bl+k);
  f32x4 b1 = *(const f32x4*)(bl+k+4);
  #pragma unroll
  for (int i=0;i<4;i++) u.s[i]   = f2b(b2f(u.s[i])  *g0[i] + b0[i]);
  #pragma unroll
  for (int i=0;i<4;i++) u.s[4+i] = f2b(b2f(u.s[4+i])*g1[i] + b1[i]);
  return u.q;
}

// ---------------- weight fp32 -> bf16 pool ----------------
__global__ __launch_bounds__(256) void conv_w(const float* w0,const float* w1,const float* w2,
                                              const float* w3,const float* w4,const float* w5,
                                              ushort* pool)
{
  size_t idx4 = (size_t)blockIdx.x*256 + threadIdx.x;
  size_t e = idx4*4;
  const float* src; size_t base;
  if      (e <  1769472u){src=w0;base=0;}
  else if (e <  2359296u){src=w1;base=1769472u;}
  else if (e <  9437184u){src=w2;base=2359296u;}
  else if (e < 16515072u){src=w3;base=9437184u;}
  else if (e < 35389440u){src=w4;base=16515072u;}
  else                   {src=w5;base=35389440u;}
  f32x4 f = *(const f32x4*)(src + (e-base));
  ushort4 u; u.x=f2b(f[0]); u.y=f2b(f[1]); u.z=f2b(f[2]); u.w=f2b(f[3]);
  *(ushort4*)(pool+e) = u;
}

// out = x + bo[col]  (pre-fill residual+bias; out-proj/expert adds are atomic)
__global__ __launch_bounds__(256) void out_init(const float* __restrict__ x, const float* __restrict__ bo,
                                                float* __restrict__ out)
{
  size_t i = ((size_t)blockIdx.x*256 + threadIdx.x)*4;
  int col = (int)(i % EDIM);
  f32x4 xv = *(const f32x4*)(x+i);
  f32x4 bv = *(const f32x4*)(bo+col);
  f32x4 r = { xv[0]+bv[0], xv[1]+bv[1], xv[2]+bv[2], xv[3]+bv[3] };
  *(f32x4*)(out+i) = r;
}

// ---------------- LayerNorm kernels (wave per token) ----------------
__global__ __launch_bounds__(256) void ln1_k(const float* __restrict__ x, const float* __restrict__ g,
                                             const float* __restrict__ b, ushort* __restrict__ out)
{
  int w = blockIdx.x*4 + (threadIdx.x>>6);
  int lane = threadIdx.x & 63;
  const float* xr = x + (size_t)w*EDIM;
  float v[12]; float s=0.f, s2=0.f;
  #pragma unroll
  for (int i=0;i<12;i++){ v[i]=xr[lane+64*i]; s+=v[i]; s2+=v[i]*v[i]; }
  #pragma unroll
  for (int o=32;o>0;o>>=1){ s += __shfl_xor(s,o); s2 += __shfl_xor(s2,o); }
  float mu = s*(1.f/768.f);
  float rs = rsqrtf(s2*(1.f/768.f) - mu*mu + 1e-5f);
  ushort* op = out + (size_t)w*EDIM;
  #pragma unroll
  for (int i=0;i<12;i++){ int d=lane+64*i; op[d] = f2b((v[i]-mu)*rs*g[d] + b[d]); }
}

__global__ __launch_bounds__(256) void ln2z_k(const float* __restrict__ x1, const float* __restrict__ g,
                                              const float* __restrict__ b, ushort* __restrict__ z)
{
  int w = blockIdx.x*4 + (threadIdx.x>>6);
  int lane = threadIdx.x & 63;
  const float* xr = x1 + (size_t)w*EDIM;
  float v[12]; float s=0.f, s2=0.f;
  #pragma unroll
  for (int i=0;i<12;i++){ v[i]=xr[lane+64*i]; s+=v[i]; s2+=v[i]*v[i]; }
  #pragma unroll
  for (int o=32;o>0;o>>=1){ s += __shfl_xor(s,o); s2 += __shfl_xor(s2,o); }
  float mu = s*(1.f/768.f);
  float rs = rsqrtf(s2*(1.f/768.f) - mu*mu + 1e-5f);
  float xn[12]; s=0.f; s2=0.f;
  #pragma unroll
  for (int i=0;i<12;i++){ int d=lane+64*i; xn[i]=(v[i]-mu)*rs*g[d]+b[d]; s+=xn[i]; s2+=xn[i]*xn[i]; }
  #pragma unroll
  for (int o=32;o>0;o>>=1){ s += __shfl_xor(s,o); s2 += __shfl_xor(s2,o); }
  float mu2 = s*(1.f/768.f);
  float rs2 = rsqrtf(s2*(1.f/768.f) - mu2*mu2 + 1e-5f);
  ushort* op = z + (size_t)w*EDIM;
  #pragma unroll
  for (int i=0;i<12;i++){ int d=lane+64*i; op[d] = f2b((xn[i]-mu2)*rs2); }
}

__global__ __launch_bounds__(256) void router_k(const float* __restrict__ x1, const float* __restrict__ g2,
                                                const float* __restrict__ b2, const float* __restrict__ rw,
                                                const float* __restrict__ rbv, float* __restrict__ coef)
{
  int w = blockIdx.x*4 + (threadIdx.x>>6);
  int lane = threadIdx.x & 63;
  const float* xr = x1 + (size_t)w*EDIM;
  float v[12]; float s=0.f, s2=0.f;
  #pragma unroll
  for (int i=0;i<12;i++){ v[i]=xr[lane+64*i]; s+=v[i]; s2+=v[i]*v[i]; }
  #pragma unroll
  for (int o=32;o>0;o>>=1){ s += __shfl_xor(s,o); s2 += __shfl_xor(s2,o); }
  float mu = s*(1.f/768.f);
  float rs = rsqrtf(s2*(1.f/768.f) - mu*mu + 1e-5f);
  float xn[12];
  #pragma unroll
  for (int i=0;i<12;i++){ int d=lane+64*i; xn[i]=(v[i]-mu)*rs*g2[d]+b2[d]; }
  float pl[8] = {0.f,0.f,0.f,0.f,0.f,0.f,0.f,0.f};
  #pragma unroll
  for (int i=0;i<12;i++){
    int d=lane+64*i; float xv=xn[i];
    #pragma unroll
    for (int e=0;e<8;e++) pl[e] += xv * rw[e*EDIM + d];
  }
  #pragma unroll
  for (int e=0;e<8;e++){
    #pragma unroll
    for (int o=32;o>0;o>>=1) pl[e] += __shfl_xor(pl[e], o);
  }
  float lgt[8]; float mx = -1e30f;
  #pragma unroll
  for (int e=0;e<8;e++){ lgt[e]=pl[e]+rbv[e]; mx = fmaxf(mx, lgt[e]); }
  float p[8]; float den=0.f;
  #pragma unroll
  for (int e=0;e<8;e++){ p[e]=__expf(lgt[e]-mx); den+=p[e]; }
  float inv = 1.f/den;
  #pragma unroll
  for (int e=0;e<8;e++) p[e]*=inv;
  int i1=0;
  #pragma unroll
  for (int e=1;e<8;e++) if (p[e]>p[i1]) i1=e;
  int i2=(i1==0)?1:0;
  #pragma unroll
  for (int e=0;e<8;e++){ if (e==i1) continue; if (p[e]>p[i2]) i2=e; }
  float w1 = 1.f/(1.f+__expf(p[i2]-p[i1]));
  float w2 = 1.f - w1;
  if (lane < 8){
    float c = (lane==i1)? w1 : ((lane==i2)? w2 : 0.f);
    coef[(size_t)w*8 + lane] = c;
  }
}

// deterministic gather lists via block-wide prefix sums (no atomics)
__global__ __launch_bounds__(256) void build_lists(const int* __restrict__ mt, const float* __restrict__ coef,
                                                   int* __restrict__ lists, int* __restrict__ cnt)
{
  const int job = blockIdx.x;       // 0: mt==0, 1: mt==1, 2..9: general expert job-2
  int* list = lists + (size_t)job*NTOK;
  __shared__ int wsum[4];
  int base = 0;
  const int lane = threadIdx.x & 63, wv = threadIdx.x >> 6;
  for (int c0=0; c0<NTOK; c0+=256){
    int t = c0 + threadIdx.x;
    bool flag;
    if (job==0)      flag = (mt[t]==0);
    else if (job==1) flag = (mt[t]==1);
    else             flag = (coef[(size_t)t*8 + (job-2)] != 0.0f);
    unsigned long long bal = __ballot(flag);
    int pre = __popcll(bal & ((1ull<<lane)-1ull));
    if (lane==0) wsum[wv] = __popcll(bal);
    __syncthreads();
    int off = base + pre;
    for (int k=0;k<wv;k++) off += wsum[k];
    int tot = wsum[0]+wsum[1]+wsum[2]+wsum[3];
    if (flag) list[off] = t;
    base += tot;
    __syncthreads();
  }
  if (threadIdx.x==0){ cnt[job+1] = base; if (job==0) cnt[0] = NTOK; }
}

// ---------------- dense MFMA GEMM (QKV): C = A@B^T + bias -> bf16 ----------------
struct GemmArgs {
  const ushort* A; const ushort* B;
  const float* bias;
  ushort* outBF;
  int K, ldc;
};

__global__ __launch_bounds__(256) void gemm_k(GemmArgs g)
{
  const int mb = blockIdx.x, nb = blockIdx.y;
  __shared__ __align__(16) ushort As[128*40];
  __shared__ __align__(16) ushort Bs[128*40];
  const int tid = threadIdx.x;
  const int lane = tid & 63, wave = tid >> 6;
  const int ar = tid >> 2, ac = tid & 3;
  const int row0 = mb*128 + ar, row1 = row0 + 64;
  const int KK = g.K;
  const ushort* Ap0 = g.A + (size_t)row0*KK + ac*8;
  const ushort* Ap1 = g.A + (size_t)row1*KK + ac*8;
  const ushort* Bp0 = g.B + (size_t)(nb*128+ar)*KK + ac*8;
  const ushort* Bp1 = Bp0 + (size_t)64*KK;
  const int nst = KK >> 5;
  uint4 ra0 = *(const uint4*)(Ap0);
  uint4 ra1 = *(const uint4*)(Ap1);
  uint4 rb0 = *(const uint4*)(Bp0);
  uint4 rb1 = *(const uint4*)(Bp1);
  f32x4 acc[4][4];
  #pragma unroll
  for (int m=0;m<4;m++)
    #pragma unroll
    for (int n=0;n<4;n++) acc[m][n] = (f32x4){0.f,0.f,0.f,0.f};
  const int fr = lane & 15, fq = lane >> 4;
  const int rb_ = (wave>>1)*64, cb_ = (wave&1)*64;
  for (int kt=0; kt<nst; ++kt){
    __syncthreads();
    *(uint4*)&As[ ar     *40 + ac*8] = ra0;
    *(uint4*)&As[(ar+64) *40 + ac*8] = ra1;
    *(uint4*)&Bs[ ar     *40 + ac*8] = rb0;
    *(uint4*)&Bs[(ar+64) *40 + ac*8] = rb1;
    if (kt+1 < nst){
      const int ko = (kt+1)*32;
      ra0 = *(const uint4*)(Ap0 + ko);
      ra1 = *(const uint4*)(Ap1 + ko);
      rb0 = *(const uint4*)(Bp0 + ko);
      rb1 = *(const uint4*)(Bp1 + ko);
    }
    __syncthreads();
    bf16x8 af[4], bfr[4];
    #pragma unroll
    for (int m=0;m<4;m++) af[m]  = *(const bf16x8*)&As[(rb_ + m*16 + fr)*40 + fq*8];
    #pragma unroll
    for (int n=0;n<4;n++) bfr[n] = *(const bf16x8*)&Bs[(cb_ + n*16 + fr)*40 + fq*8];
    #pragma unroll
    for (int m=0;m<4;m++)
      #pragma unroll
      for (int n=0;n<4;n++)
        acc[m][n] = __builtin_amdgcn_mfma_f32_16x16x32_bf16(af[m], bfr[n], acc[m][n], 0, 0, 0);
  }
  #pragma unroll
  for (int m=0;m<4;m++){
    #pragma unroll
    for (int j=0;j<4;j++){
      const int row = mb*128 + rb_ + m*16 + fq*4 + j;
      #pragma unroll
      for (int n=0;n<4;n++){
        const int col = nb*128 + cb_ + n*16 + fr;
        g.outBF[(size_t)row*g.ldc + col] = f2b(acc[m][n][j] + g.bias[col]);
      }
    }
  }
}

// ---------------- grouped expert FFN kernels ----------------
struct FArgs {
  const ushort* z; ushort* hidden; const ushort* ctx; const ushort* wo;
  float* out;
  const int* lists; const int* cnt; const float* coef;
  const ushort* sw1; const ushort* gw1; const ushort* sw2; const ushort* gw2;
  const float* sb1; const float* gb1; const float* sb2; const float* gb2;
  const float* slg; const float* slb; const float* glg; const float* glb;
  int jobBase; int compact;
};

__device__ __forceinline__ size_t job_hoff(const FArgs& a, int job){
  size_t h = 0;
  if (a.compact){
    if (job==1) h = NTOK;
    else if (job==2) h = NTOK + (size_t)a.cnt[1];
    else if (job>=3){ for (int k=3;k<job;k++) h += (size_t)a.cnt[k]; }
  }
  return h;
}

// FFN1: hidden[hoff+row] = gelu( (lg*z[tok]+lb) @ W1^T + b1 ), grid (64,24,J)
__global__ __launch_bounds__(256) void ffn1_k(FArgs a)
{
  const int job = a.jobBase + blockIdx.z;
  const int cntj = (job==0) ? NTOK : a.cnt[job];
  const int mb = blockIdx.x, nb = blockIdx.y;
  if (mb*128 >= cntj) return;
  const int* list = (job==0) ? nullptr : a.lists + (size_t)(job-1)*NTOK;
  const ushort* B; const float* bias; const float* lg; const float* lb;
  if (job<3){ B=a.sw1+(size_t)job*FDIM*EDIM; bias=a.sb1+(size_t)job*FDIM; lg=a.slg+(size_t)job*EDIM; lb=a.slb+(size_t)job*EDIM; }
  else { int ge=job-3; B=a.gw1+(size_t)ge*FDIM*EDIM; bias=a.gb1+(size_t)ge*FDIM; lg=a.glg+(size_t)ge*EDIM; lb=a.glb+(size_t)ge*EDIM; }
  const size_t hoff = job_hoff(a, job);
  __shared__ __align__(16) ushort As[128*40];
  __shared__ __align__(16) ushort Bs[128*40];
  const int tid = threadIdx.x;
  const int lane = tid & 63, wave = tid >> 6;
  const int ar = tid >> 2, ac = tid & 3;
  const int row0 = mb*128 + ar, row1 = row0 + 64;
  const int t0 = list ? list[min(row0,cntj-1)] : min(row0,cntj-1);
  const int t1 = list ? list[min(row1,cntj-1)] : min(row1,cntj-1);
  const ushort* Ap0 = a.z + (size_t)t0*EDIM + ac*8;
  const ushort* Ap1 = a.z + (size_t)t1*EDIM + ac*8;
  const ushort* Bp0 = B + (size_t)(nb*128+ar)*EDIM + ac*8;
  const ushort* Bp1 = Bp0 + (size_t)64*EDIM;
  uint4 ra0 = *(const uint4*)(Ap0);
  uint4 ra1 = *(const uint4*)(Ap1);
  uint4 rb0 = *(const uint4*)(Bp0);
  uint4 rb1 = *(const uint4*)(Bp1);
  { int k0 = ac*8; ra0 = fold8(ra0,lg,lb,k0); ra1 = fold8(ra1,lg,lb,k0); }
  f32x4 acc[4][4];
  #pragma unroll
  for (int m=0;m<4;m++)
    #pragma unroll
    for (int n=0;n<4;n++) acc[m][n] = (f32x4){0.f,0.f,0.f,0.f};
  const int fr = lane & 15, fq = lane >> 4;
  const int rb_ = (wave>>1)*64, cb_ = (wave&1)*64;
  for (int kt=0; kt<24; ++kt){
    __syncthreads();
    *(uint4*)&As[ ar     *40 + ac*8] = ra0;
    *(uint4*)&As[(ar+64) *40 + ac*8] = ra1;
    *(uint4*)&Bs[ ar     *40 + ac*8] = rb0;
    *(uint4*)&Bs[(ar+64) *40 + ac*8] = rb1;
    if (kt+1 < 24){
      const int ko = (kt+1)*32;
      ra0 = *(const uint4*)(Ap0 + ko);
      ra1 = *(const uint4*)(Ap1 + ko);
      rb0 = *(const uint4*)(Bp0 + ko);
      rb1 = *(const uint4*)(Bp1 + ko);
      { int k0 = ko + ac*8; ra0 = fold8(ra0,lg,lb,k0); ra1 = fold8(ra1,lg,lb,k0); }
    }
    __syncthreads();
    bf16x8 af[4], bfr[4];
    #pragma unroll
    for (int m=0;m<4;m++) af[m]  = *(const bf16x8*)&As[(rb_ + m*16 + fr)*40 + fq*8];
    #pragma unroll
    for (int n=0;n<4;n++) bfr[n] = *(const bf16x8*)&Bs[(cb_ + n*16 + fr)*40 + fq*8];
    #pragma unroll
    for (int m=0;m<4;m++)
      #pragma unroll
      for (int n=0;n<4;n++)
        acc[m][n] = __builtin_amdgcn_mfma_f32_16x16x32_bf16(af[m], bfr[n], acc[m][n], 0, 0, 0);
  }
  #pragma unroll
  for (int m=0;m<4;m++){
    #pragma unroll
    for (int j=0;j<4;j++){
      const int row = mb*128 + rb_ + m*16 + fq*4 + j;
      if (row < cntj){
        #pragma unroll
        for (int n=0;n<4;n++){
          const int col = nb*128 + cb_ + n*16 + fr;
          a.hidden[(hoff+row)*FDIM + col] = f2b(gelu_f(acc[m][n][j] + bias[col]));
        }
      }
    }
  }
}

// FFN2 / out-proj: atomic scatter-add GEMM, split-K=2. grid (64, 6, J*2) or (64,6,2) for jobBase=-1.
__global__ __launch_bounds__(256) void ffn2_k(FArgs a)
{
  const int zb = blockIdx.z;
  const bool op = (a.jobBase < 0);
  const int job = op ? -1 : a.jobBase + (zb>>1);
  const int ks = zb & 1;
  const int cntj = op ? NTOK : ((job==0) ? NTOK : a.cnt[job]);
  const int mb = blockIdx.x, nb = blockIdx.y;
  if (mb*128 >= cntj) return;
  const int* list = (op || job==0) ? nullptr : a.lists + (size_t)(job-1)*NTOK;
  const ushort* Abase; int lda; const ushort* B; const float* bias = nullptr;
  const float* coefp = nullptr; int eidx = 0; int kLen;
  if (op){ Abase = a.ctx; lda = EDIM; B = a.wo; kLen = EDIM/2; }
  else {
    lda = FDIM; kLen = FDIM/2;
    Abase = a.hidden + job_hoff(a, job)*FDIM;
    if (job<3){ B=a.sw2+(size_t)job*(size_t)EDIM*FDIM; bias=a.sb2+(size_t)job*EDIM; }
    else { eidx=job-3; B=a.gw2+(size_t)eidx*(size_t)EDIM*FDIM; bias=a.gb2+(size_t)eidx*EDIM; coefp=a.coef; }
  }
  const int kOff = ks*kLen;
  const int nst = kLen >> 5;
  __shared__ __align__(16) ushort As[128*40];
  __shared__ __align__(16) ushort Bs[128*40];
  const int tid = threadIdx.x;
  const int lane = tid & 63, wave = tid >> 6;
  const int ar = tid >> 2, ac = tid & 3;
  const int row0 = mb*128 + ar, row1 = row0 + 64;
  const ushort* Ap0 = Abase + (size_t)min(row0,cntj-1)*lda + kOff + ac*8;
  const ushort* Ap1 = Abase + (size_t)min(row1,cntj-1)*lda + kOff + ac*8;
  const ushort* Bp0 = B + (size_t)(nb*128+ar)*lda + kOff + ac*8;
  const ushort* Bp1 = Bp0 + (size_t)64*lda;
  uint4 ra0 = *(const uint4*)(Ap0);
  uint4 ra1 = *(const uint4*)(Ap1);
  uint4 rb0 = *(const uint4*)(Bp0);
  uint4 rb1 = *(const uint4*)(Bp1);
  f32x4 acc[4][4];
  #pragma unroll
  for (int m=0;m<4;m++)
    #pragma unroll
    for (int n=0;n<4;n++) acc[m][n] = (f32x4){0.f,0.f,0.f,0.f};
  const int fr = lane & 15, fq = lane >> 4;
  const int rb_ = (wave>>1)*64, cb_ = (wave&1)*64;
  for (int kt=0; kt<nst; ++kt){
    __syncthreads();
    *(uint4*)&As[ ar     *40 + ac*8] = ra0;
    *(uint4*)&As[(ar+64) *40 + ac*8] = ra1;
    *(uint4*)&Bs[ ar     *40 + ac*8] = rb0;
    *(uint4*)&Bs[(ar+64) *40 + ac*8] = rb1;
    if (kt+1 < nst){
      const int ko = (kt+1)*32;
      ra0 = *(const uint4*)(Ap0 + ko);
      ra1 = *(const uint4*)(Ap1 + ko);
      rb0 = *(const uint4*)(Bp0 + ko);
      rb1 = *(const uint4*)(Bp1 + ko);
    }
    __syncthreads();
    bf16x8 af[4], bfr[4];
    #pragma unroll
    for (int m=0;m<4;m++) af[m]  = *(const bf16x8*)&As[(rb_ + m*16 + fr)*40 + fq*8];
    #pragma unroll
    for (int n=0;n<4;n++) bfr[n] = *(const bf16x8*)&Bs[(cb_ + n*16 + fr)*40 + fq*8];
    #pragma unroll
    for (int m=0;m<4;m++)
      #pragma unroll
      for (int n=0;n<4;n++)
        acc[m][n] = __builtin_amdgcn_mfma_f32_16x16x32_bf16(af[m], bfr[n], acc[m][n], 0, 0, 0);
  }
  #pragma unroll
  for (int m=0;m<4;m++){
    #pragma unroll
    for (int j=0;j<4;j++){
      const int row = mb*128 + rb_ + m*16 + fq*4 + j;
      if (row < cntj){
        const int tok = list ? list[row] : row;
        const float c = coefp ? coefp[(size_t)tok*8 + eidx] : 1.0f;
        #pragma unroll
        for (int n=0;n<4;n++){
          const int col = nb*128 + cb_ + n*16 + fr;
          float v = acc[m][n][j];
          if (bias && ks==0) v += bias[col];
          atomicAdd(&a.out[(size_t)tok*EDIM + col], c*v);
        }
      }
    }
  }
}

// ---------------- MFMA flash attention (unchanged from round 3) ----------------
__global__ __launch_bounds__(256) void attn_k(const ushort* __restrict__ qkv, ushort* __restrict__ ctx)
{
  const int qb = blockIdx.x, bh = blockIdx.y;
  const int b = bh/12, h = bh%12;
  const int tid = threadIdx.x;
  const int lane = tid & 63, w = tid >> 6;
  const int fr = lane & 15, fq = lane >> 4;
  __shared__ __align__(16) ushort Ks[4096];
  __shared__ __align__(16) ushort Vts[4096];
  __shared__ __align__(16) ushort Ps[4096];
  const size_t tokq = (size_t)b*1024 + (size_t)qb*64;

  bf16x8 qf[2];
  {
    const ushort* qp = qkv + (tokq + w*16 + fr)*2304 + h*64 + fq*8;
    qf[0] = *(const bf16x8*)(qp);
    qf[1] = *(const bf16x8*)(qp + 32);
  }
  f32x4 o[4];
  #pragma unroll
  for (int nt=0;nt<4;nt++) o[nt] = (f32x4){0.f,0.f,0.f,0.f};
  float m[4] = {-1e30f,-1e30f,-1e30f,-1e30f};
  float l[4] = {0.f,0.f,0.f,0.f};

  const int skr = tid>>3, skc = (tid&7)*8;
  const int svd = (tid&15)*4, svk = (tid>>4)*4;

  for (int kt=0; kt<16; ++kt){
    __syncthreads();
    const size_t tokk = (size_t)b*1024 + (size_t)kt*64;
    #pragma unroll
    for (int p=0;p<2;p++){
      int row = skr + p*32;
      uint4 kq = *(const uint4*)(qkv + (tokk+row)*2304 + 768 + h*64 + skc);
      *(uint4*)&Ks[row*64 + (skc ^ ((row&7)<<3))] = kq;
    }
    {
      union { ushort4 v4[4]; ushort s[16]; } tv;
      #pragma unroll
      for (int i=0;i<4;i++)
        tv.v4[i] = *(const ushort4*)(qkv + (tokk+svk+i)*2304 + 1536 + h*64 + svd);
      #pragma unroll
      for (int j=0;j<4;j++){
        ushort4 tj; tj.x=tv.s[j]; tj.y=tv.s[4+j]; tj.z=tv.s[8+j]; tj.w=tv.s[12+j];
        int dr = svd + j;
        *(ushort4*)&Vts[dr*64 + (svk ^ ((dr&7)<<3))] = tj;
      }
    }
    __syncthreads();
    f32x4 s[4];
    #pragma unroll
    for (int nt=0;nt<4;nt++){
      s[nt] = (f32x4){0.f,0.f,0.f,0.f};
      int kr = nt*16 + fr;
      const ushort* kb = &Ks[kr*64];
      int sw = (kr&7)<<3;
      bf16x8 k0 = *(const bf16x8*)&kb[(fq*8) ^ sw];
      bf16x8 k1 = *(const bf16x8*)&kb[(fq*8+32) ^ sw];
      s[nt] = __builtin_amdgcn_mfma_f32_16x16x32_bf16(qf[0], k0, s[nt], 0,0,0);
      s[nt] = __builtin_amdgcn_mfma_f32_16x16x32_bf16(qf[1], k1, s[nt], 0,0,0);
    }
    float a_[4], pr[4][4];
    #pragma unroll
    for (int j=0;j<4;j++){
      float mx = fmaxf(fmaxf(s[0][j],s[1][j]), fmaxf(s[2][j],s[3][j])) * 0.125f;
      mx = fmaxf(mx, __shfl_xor(mx,1));
      mx = fmaxf(mx, __shfl_xor(mx,2));
      mx = fmaxf(mx, __shfl_xor(mx,4));
      mx = fmaxf(mx, __shfl_xor(mx,8));
      float mn = fmaxf(m[j], mx);
      float a = __expf(m[j] - mn);
      m[j] = mn; a_[j] = a;
      float ss = 0.f;
      #pragma unroll
      for (int nt=0;nt<4;nt++){
        float p = __expf(s[nt][j]*0.125f - mn);
        pr[nt][j] = p; ss += p;
      }
      ss += __shfl_xor(ss,1);
      ss += __shfl_xor(ss,2);
      ss += __shfl_xor(ss,4);
      ss += __shfl_xor(ss,8);
      l[j] = l[j]*a + ss;
    }
    #pragma unroll
    for (int nt=0;nt<4;nt++){
      #pragma unroll
      for (int j=0;j<4;j++){
        int row = fq*4 + j;
        Ps[w*1024 + row*64 + ((nt*16+fr) ^ ((row&7)<<3))] = f2b(pr[nt][j]);
        o[nt][j] *= a_[j];
      }
    }
    #pragma unroll
    for (int ks=0; ks<2; ++ks){
      int kvo = ks*32 + fq*8;
      bf16x8 pf = *(const bf16x8*)&Ps[w*1024 + fr*64 + (kvo ^ ((fr&7)<<3))];
      #pragma unroll
      for (int nt=0;nt<4;nt++){
        int dr = nt*16 + fr;
        bf16x8 vf = *(const bf16x8*)&Vts[dr*64 + (kvo ^ ((dr&7)<<3))];
        o[nt] = __builtin_amdgcn_mfma_f32_16x16x32_bf16(pf, vf, o[nt], 0,0,0);
      }
    }
  }
  float inv[4];
  #pragma unroll
  for (int j=0;j<4;j++) inv[j] = 1.f/l[j];
  ushort* cp = ctx + (tokq + w*16)*768 + h*64;
  #pragma unroll
  for (int nt=0;nt<4;nt++){
    #pragma unroll
    for (int j=0;j<4;j++){
      cp[(size_t)(fq*4+j)*768 + nt*16 + fr] = f2b(o[nt][j]*inv[j]);
    }
  }
}

// ---------------- workspace layout ----------------
#define OFF_POOL   0u
#define OFF_Z      108527616u
#define OFF_COEF   121110528u
#define OFF_LISTS  121372672u
#define OFF_CNT    121700352u
#define OFF_QKV    121700608u
#define OFF_CTX    159449344u
#define OFF_XN1    172032256u
#define WS_FALLBACK 184615168u
#define WS_GROUPED  222363904u   // OFF_QKV + 16384*3072*2

extern "C" void kernel_launch(void* const* d_in, const int* in_sizes, int n_in,
                              void* d_out, int out_size, void* d_ws, size_t ws_size,
                              hipStream_t stream)
{
  const float* x    = (const float*)d_in[0];
  const int*   mt   = (const int*)d_in[1];
  const float* n1g  = (const float*)d_in[2];
  const float* n1b  = (const float*)d_in[3];
  const float* n2g  = (const float*)d_in[4];
  const float* n2b  = (const float*)d_in[5];
  const float* wqkv = (const float*)d_in[6];
  const float* bqkv = (const float*)d_in[7];
  const float* wo   = (const float*)d_in[8];
  const float* bo   = (const float*)d_in[9];
  const float* rw   = (const float*)d_in[10];
  const float* rb   = (const float*)d_in[11];
  const float* slg  = (const float*)d_in[12];
  const float* slb  = (const float*)d_in[13];
  const float* sw1  = (const float*)d_in[14];
  const float* sb1  = (const float*)d_in[15];
  const float* sw2  = (const float*)d_in[16];
  const float* sb2  = (const float*)d_in[17];
  const float* glg  = (const float*)d_in[18];
  const float* glb  = (const float*)d_in[19];
  const float* gw1  = (const float*)d_in[20];
  const float* gb1  = (const float*)d_in[21];
  const float* gw2  = (const float*)d_in[22];
  const float* gb2  = (const float*)d_in[23];
  float* out = (float*)d_out;
  char* ws = (char*)d_ws;

  ushort* pool  = (ushort*)(ws + OFF_POOL);
  ushort* z     = (ushort*)(ws + OFF_Z);
  float*  coef  = (float*) (ws + OFF_COEF);
  int*    lists = (int*)   (ws + OFF_LISTS);
  int*    cnt   = (int*)   (ws + OFF_CNT);
  ushort* qkv   = (ushort*)(ws + OFF_QKV);
  ushort* ctx   = (ushort*)(ws + OFF_CTX);
  ushort* xn1   = (ushort*)(ws + OFF_XN1);
  ushort* hidden= (ushort*)(ws + OFF_QKV);   // aliases qkv/ctx/xn1 (dead by expert phase)

  ushort* pWqkv = pool + 0;
  ushort* pWo   = pool + 1769472;
  ushort* pSw1  = pool + 2359296;
  ushort* pSw2  = pool + 9437184;
  ushort* pGw1  = pool + 16515072;
  ushort* pGw2  = pool + 35389440;

  const bool grouped = (ws_size >= (size_t)WS_GROUPED);

  conv_w<<<52992, 256, 0, stream>>>(wqkv, wo, sw1, sw2, gw1, gw2, pool);
  ln1_k<<<2048, 256, 0, stream>>>(x, n1g, n1b, xn1);
  { GemmArgs a{}; a.A=xn1; a.B=pWqkv; a.bias=bqkv; a.outBF=qkv; a.K=768; a.ldc=2304;
    gemm_k<<<dim3(64,18),256,0,stream>>>(a); }
  attn_k<<<dim3(16,96),256,0,stream>>>(qkv, ctx);
  out_init<<<6144,256,0,stream>>>(x, bo, out);

  FArgs fa{};
  fa.z=z; fa.hidden=hidden; fa.ctx=ctx; fa.wo=pWo; fa.out=out;
  fa.lists=lists; fa.cnt=cnt; fa.coef=coef;
  fa.sw1=pSw1; fa.gw1=pGw1; fa.sw2=pSw2; fa.gw2=pGw2;
  fa.sb1=sb1; fa.gb1=gb1; fa.sb2=sb2; fa.gb2=gb2;
  fa.slg=slg; fa.slb=slb; fa.glg=glg; fa.glb=glb;

  // out-proj: atomic split-K2 (out pre-filled with x + bo)
  { FArgs a = fa; a.jobBase = -1; a.compact = 0;
    ffn2_k<<<dim3(64,6,2),256,0,stream>>>(a); }

  ln2z_k<<<2048,256,0,stream>>>(out, n2g, n2b, z);
  router_k<<<2048,256,0,stream>>>(out, n2g, n2b, rw, rb, coef);
  build_lists<<<10,256,0,stream>>>(mt, coef, lists, cnt);

  if (grouped){
    { FArgs a = fa; a.jobBase = 0; a.compact = 1;
      ffn1_k<<<dim3(64,24,3),256,0,stream>>>(a);
      ffn2_k<<<dim3(64,6,6),256,0,stream>>>(a); }
    { FArgs a = fa; a.jobBase = 3; a.compact = 1;
      ffn1_k<<<dim3(64,24,8),256,0,stream>>>(a);
      ffn2_k<<<dim3(64,6,16),256,0,stream>>>(a); }
  } else {
    for (int j=0;j<11;j++){
      FArgs a = fa; a.jobBase = j; a.compact = 0;
      ffn1_k<<<dim3(64,24,1),256,0,stream>>>(a);
      ffn2_k<<<dim3(64,6,2),256,0,stream>>>(a);
    }
  }
}

// Round 5
// 1258.367 us; speedup vs baseline: 1.9766x; 1.0600x over previous
//
#include <hip/hip_runtime.h>
#include <cstdint>

#define NTOK 8192
#define EDIM 768
#define FDIM 3072

using bf16x8 = __attribute__((ext_vector_type(8))) __bf16;
using f32x4  = __attribute__((ext_vector_type(4))) float;

__device__ __forceinline__ float b2f(ushort u){ union{uint32_t i; float f;} v; v.i = ((uint32_t)u)<<16; return v.f; }
__device__ __forceinline__ ushort f2b(float f){ union{float f; uint32_t i;} v; v.f=f; uint32_t r = v.i + 0x7fffu + ((v.i>>16)&1u); return (ushort)(r>>16); }
__device__ __forceinline__ float gelu_f(float v){ return 0.5f*v*(1.0f+erff(v*0.70710678118654752f)); }

// ---------------- weight fp32 -> bf16 pool (LN gains folded into W1 rows) ----------------
__global__ __launch_bounds__(256) void conv_w(const float* w0,const float* w1,const float* w2,
                                              const float* w3,const float* w4,const float* w5,
                                              const float* slg, const float* glg,
                                              ushort* pool)
{
  size_t idx4 = (size_t)blockIdx.x*256 + threadIdx.x;
  size_t e = idx4*4;
  const float* src; size_t base; int region;
  if      (e <  1769472u){src=w0;base=0;        region=0;}
  else if (e <  2359296u){src=w1;base=1769472u; region=1;}
  else if (e <  9437184u){src=w2;base=2359296u; region=2;}
  else if (e < 16515072u){src=w3;base=9437184u; region=3;}
  else if (e < 35389440u){src=w4;base=16515072u;region=4;}
  else                   {src=w5;base=35389440u;region=5;}
  size_t within = e - base;
  f32x4 f = *(const f32x4*)(src + within);
  if (region==2){
    int ex = (int)(within/2359296u); int col = (int)(within%768u);
    f32x4 g = *(const f32x4*)(slg + ex*768 + col);
    f[0]*=g[0]; f[1]*=g[1]; f[2]*=g[2]; f[3]*=g[3];
  } else if (region==4){
    int ex = (int)(within/2359296u); int col = (int)(within%768u);
    f32x4 g = *(const f32x4*)(glg + ex*768 + col);
    f[0]*=g[0]; f[1]*=g[1]; f[2]*=g[2]; f[3]*=g[3];
  }
  ushort4 u; u.x=f2b(f[0]); u.y=f2b(f[1]); u.z=f2b(f[2]); u.w=f2b(f[3]);
  *(ushort4*)(pool+e) = u;
}

// b1p[j*FDIM+f] = b1[j][f] + W1[j][f][:] . lb[j][:]   (11 experts: 3 spec + 8 gen)
__global__ __launch_bounds__(256) void b1fold_k(const float* __restrict__ sw1, const float* __restrict__ gw1,
                                                const float* __restrict__ sb1, const float* __restrict__ gb1,
                                                const float* __restrict__ slb, const float* __restrict__ glb,
                                                float* __restrict__ b1p)
{
  int j = blockIdx.x*4 + (threadIdx.x>>6);   // 0 .. 11*3072-1
  int lane = threadIdx.x & 63;
  int je = j / FDIM, f = j % FDIM;
  const float* wrow = (je<3) ? sw1 + ((size_t)je*FDIM + f)*EDIM : gw1 + ((size_t)(je-3)*FDIM + f)*EDIM;
  const float* lb   = (je<3) ? slb + (size_t)je*EDIM : glb + (size_t)(je-3)*EDIM;
  float s = 0.f;
  #pragma unroll
  for (int i=0;i<12;i++){ int d = lane + 64*i; s += wrow[d]*lb[d]; }
  #pragma unroll
  for (int o=32;o>0;o>>=1) s += __shfl_xor(s,o);
  if (lane==0){
    float base = (je<3) ? sb1[je*FDIM+f] : gb1[(je-3)*FDIM+f];
    b1p[j] = base + s;
  }
}

// out = x + bo[col]
__global__ __launch_bounds__(256) void out_init(const float* __restrict__ x, const float* __restrict__ bo,
                                                float* __restrict__ out)
{
  size_t i = ((size_t)blockIdx.x*256 + threadIdx.x)*4;
  int col = (int)(i % EDIM);
  f32x4 xv = *(const f32x4*)(x+i);
  f32x4 bv = *(const f32x4*)(bo+col);
  f32x4 r = { xv[0]+bv[0], xv[1]+bv[1], xv[2]+bv[2], xv[3]+bv[3] };
  *(f32x4*)(out+i) = r;
}

// ---------------- LayerNorm kernels (wave per token) ----------------
__global__ __launch_bounds__(256) void ln1_k(const float* __restrict__ x, const float* __restrict__ g,
                                             const float* __restrict__ b, ushort* __restrict__ out)
{
  int w = blockIdx.x*4 + (threadIdx.x>>6);
  int lane = threadIdx.x & 63;
  const float* xr = x + (size_t)w*EDIM;
  float v[12]; float s=0.f, s2=0.f;
  #pragma unroll
  for (int i=0;i<12;i++){ v[i]=xr[lane+64*i]; s+=v[i]; s2+=v[i]*v[i]; }
  #pragma unroll
  for (int o=32;o>0;o>>=1){ s += __shfl_xor(s,o); s2 += __shfl_xor(s2,o); }
  float mu = s*(1.f/768.f);
  float rs = rsqrtf(s2*(1.f/768.f) - mu*mu + 1e-5f);
  ushort* op = out + (size_t)w*EDIM;
  #pragma unroll
  for (int i=0;i<12;i++){ int d=lane+64*i; op[d] = f2b((v[i]-mu)*rs*g[d] + b[d]); }
}

__global__ __launch_bounds__(256) void ln2z_k(const float* __restrict__ x1, const float* __restrict__ g,
                                              const float* __restrict__ b, ushort* __restrict__ z)
{
  int w = blockIdx.x*4 + (threadIdx.x>>6);
  int lane = threadIdx.x & 63;
  const float* xr = x1 + (size_t)w*EDIM;
  float v[12]; float s=0.f, s2=0.f;
  #pragma unroll
  for (int i=0;i<12;i++){ v[i]=xr[lane+64*i]; s+=v[i]; s2+=v[i]*v[i]; }
  #pragma unroll
  for (int o=32;o>0;o>>=1){ s += __shfl_xor(s,o); s2 += __shfl_xor(s2,o); }
  float mu = s*(1.f/768.f);
  float rs = rsqrtf(s2*(1.f/768.f) - mu*mu + 1e-5f);
  float xn[12]; s=0.f; s2=0.f;
  #pragma unroll
  for (int i=0;i<12;i++){ int d=lane+64*i; xn[i]=(v[i]-mu)*rs*g[d]+b[d]; s+=xn[i]; s2+=xn[i]*xn[i]; }
  #pragma unroll
  for (int o=32;o>0;o>>=1){ s += __shfl_xor(s,o); s2 += __shfl_xor(s2,o); }
  float mu2 = s*(1.f/768.f);
  float rs2 = rsqrtf(s2*(1.f/768.f) - mu2*mu2 + 1e-5f);
  ushort* op = z + (size_t)w*EDIM;
  #pragma unroll
  for (int i=0;i<12;i++){ int d=lane+64*i; op[d] = f2b((xn[i]-mu2)*rs2); }
}

__global__ __launch_bounds__(256) void router_k(const float* __restrict__ x1, const float* __restrict__ g2,
                                                const float* __restrict__ b2, const float* __restrict__ rw,
                                                const float* __restrict__ rbv, float* __restrict__ coef)
{
  int w = blockIdx.x*4 + (threadIdx.x>>6);
  int lane = threadIdx.x & 63;
  const float* xr = x1 + (size_t)w*EDIM;
  float v[12]; float s=0.f, s2=0.f;
  #pragma unroll
  for (int i=0;i<12;i++){ v[i]=xr[lane+64*i]; s+=v[i]; s2+=v[i]*v[i]; }
  #pragma unroll
  for (int o=32;o>0;o>>=1){ s += __shfl_xor(s,o); s2 += __shfl_xor(s2,o); }
  float mu = s*(1.f/768.f);
  float rs = rsqrtf(s2*(1.f/768.f) - mu*mu + 1e-5f);
  float xn[12];
  #pragma unroll
  for (int i=0;i<12;i++){ int d=lane+64*i; xn[i]=(v[i]-mu)*rs*g2[d]+b2[d]; }
  float pl[8] = {0.f,0.f,0.f,0.f,0.f,0.f,0.f,0.f};
  #pragma unroll
  for (int i=0;i<12;i++){
    int d=lane+64*i; float xv=xn[i];
    #pragma unroll
    for (int e=0;e<8;e++) pl[e] += xv * rw[e*EDIM + d];
  }
  #pragma unroll
  for (int e=0;e<8;e++){
    #pragma unroll
    for (int o=32;o>0;o>>=1) pl[e] += __shfl_xor(pl[e], o);
  }
  float lgt[8]; float mx = -1e30f;
  #pragma unroll
  for (int e=0;e<8;e++){ lgt[e]=pl[e]+rbv[e]; mx = fmaxf(mx, lgt[e]); }
  float p[8]; float den=0.f;
  #pragma unroll
  for (int e=0;e<8;e++){ p[e]=__expf(lgt[e]-mx); den+=p[e]; }
  float inv = 1.f/den;
  #pragma unroll
  for (int e=0;e<8;e++) p[e]*=inv;
  int i1=0;
  #pragma unroll
  for (int e=1;e<8;e++) if (p[e]>p[i1]) i1=e;
  int i2=(i1==0)?1:0;
  #pragma unroll
  for (int e=0;e<8;e++){ if (e==i1) continue; if (p[e]>p[i2]) i2=e; }
  float w1 = 1.f/(1.f+__expf(p[i2]-p[i1]));
  float w2 = 1.f - w1;
  if (lane < 8){
    float c = (lane==i1)? w1 : ((lane==i2)? w2 : 0.f);
    coef[(size_t)w*8 + lane] = c;
  }
}

// deterministic gather lists via block-wide prefix sums (no atomics); lists are ushort (tok < 8192)
__global__ __launch_bounds__(256) void build_lists(const int* __restrict__ mt, const float* __restrict__ coef,
                                                   ushort* __restrict__ lists, int* __restrict__ cnt)
{
  const int job = blockIdx.x;       // 0: mt==0, 1: mt==1, 2..9: general expert job-2
  ushort* list = lists + (size_t)job*NTOK;
  __shared__ int wsum[4];
  int base = 0;
  const int lane = threadIdx.x & 63, wv = threadIdx.x >> 6;
  for (int c0=0; c0<NTOK; c0+=256){
    int t = c0 + threadIdx.x;
    bool flag;
    if (job==0)      flag = (mt[t]==0);
    else if (job==1) flag = (mt[t]==1);
    else             flag = (coef[(size_t)t*8 + (job-2)] != 0.0f);
    unsigned long long bal = __ballot(flag);
    int pre = __popcll(bal & ((1ull<<lane)-1ull));
    if (lane==0) wsum[wv] = __popcll(bal);
    __syncthreads();
    int off = base + pre;
    for (int k=0;k<wv;k++) off += wsum[k];
    int tot = wsum[0]+wsum[1]+wsum[2]+wsum[3];
    if (flag) list[off] = (ushort)t;
    base += tot;
    __syncthreads();
  }
  if (threadIdx.x==0){ cnt[job+1] = base; if (job==0) cnt[0] = NTOK; }
}

// ---------------- dense MFMA GEMM (QKV): C = A@B^T + bias -> bf16 ----------------
struct GemmArgs {
  const ushort* A; const ushort* B;
  const float* bias;
  ushort* outBF;
  int K, ldc;
};

__global__ __launch_bounds__(256) void gemm_k(GemmArgs g)
{
  const int mb = blockIdx.x, nb = blockIdx.y;
  __shared__ __align__(16) ushort As[128*40];
  __shared__ __align__(16) ushort Bs[128*40];
  const int tid = threadIdx.x;
  const int lane = tid & 63, wave = tid >> 6;
  const int ar = tid >> 2, ac = tid & 3;
  const int row0 = mb*128 + ar, row1 = row0 + 64;
  const int KK = g.K;
  const ushort* Ap0 = g.A + (size_t)row0*KK + ac*8;
  const ushort* Ap1 = g.A + (size_t)row1*KK + ac*8;
  const ushort* Bp0 = g.B + (size_t)(nb*128+ar)*KK + ac*8;
  const ushort* Bp1 = Bp0 + (size_t)64*KK;
  const int nst = KK >> 5;
  uint4 ra0 = *(const uint4*)(Ap0);
  uint4 ra1 = *(const uint4*)(Ap1);
  uint4 rb0 = *(const uint4*)(Bp0);
  uint4 rb1 = *(const uint4*)(Bp1);
  f32x4 acc[4][4];
  #pragma unroll
  for (int m=0;m<4;m++)
    #pragma unroll
    for (int n=0;n<4;n++) acc[m][n] = (f32x4){0.f,0.f,0.f,0.f};
  const int fr = lane & 15, fq = lane >> 4;
  const int rb_ = (wave>>1)*64, cb_ = (wave&1)*64;
  for (int kt=0; kt<nst; ++kt){
    __syncthreads();
    *(uint4*)&As[ ar     *40 + ac*8] = ra0;
    *(uint4*)&As[(ar+64) *40 + ac*8] = ra1;
    *(uint4*)&Bs[ ar     *40 + ac*8] = rb0;
    *(uint4*)&Bs[(ar+64) *40 + ac*8] = rb1;
    if (kt+1 < nst){
      const int ko = (kt+1)*32;
      ra0 = *(const uint4*)(Ap0 + ko);
      ra1 = *(const uint4*)(Ap1 + ko);
      rb0 = *(const uint4*)(Bp0 + ko);
      rb1 = *(const uint4*)(Bp1 + ko);
    }
    __syncthreads();
    bf16x8 af[4], bfr[4];
    #pragma unroll
    for (int m=0;m<4;m++) af[m]  = *(const bf16x8*)&As[(rb_ + m*16 + fr)*40 + fq*8];
    #pragma unroll
    for (int n=0;n<4;n++) bfr[n] = *(const bf16x8*)&Bs[(cb_ + n*16 + fr)*40 + fq*8];
    #pragma unroll
    for (int m=0;m<4;m++)
      #pragma unroll
      for (int n=0;n<4;n++)
        acc[m][n] = __builtin_amdgcn_mfma_f32_16x16x32_bf16(af[m], bfr[n], acc[m][n], 0, 0, 0);
  }
  #pragma unroll
  for (int m=0;m<4;m++){
    #pragma unroll
    for (int j=0;j<4;j++){
      const int row = mb*128 + rb_ + m*16 + fq*4 + j;
      #pragma unroll
      for (int n=0;n<4;n++){
        const int col = nb*128 + cb_ + n*16 + fr;
        g.outBF[(size_t)row*g.ldc + col] = f2b(acc[m][n][j] + g.bias[col]);
      }
    }
  }
}

// ---------------- grouped expert FFN kernels ----------------
struct FArgs {
  const ushort* z; ushort* hidden; const ushort* ctx; const ushort* wo;
  float* out;
  const ushort* lists; const int* cnt; const float* coef;
  const ushort* sw1; const ushort* gw1; const ushort* sw2; const ushort* gw2;
  const float* b1p; const float* sb2; const float* gb2;
  int jobBase; int compact;
};

__device__ __forceinline__ size_t job_hoff(const FArgs& a, int job){
  size_t h = 0;
  if (a.compact){
    if (job==1) h = NTOK;
    else if (job==2) h = NTOK + (size_t)a.cnt[1];
    else if (job>=3){ for (int k=3;k<job;k++) h += (size_t)a.cnt[k]; }
  }
  return h;
}

// FFN1: hidden[hoff+row] = gelu( z[tok] @ W1'^T + b1p ), grid (64,24,J); W1' has lg folded, b1p has lb folded
__global__ __launch_bounds__(256) void ffn1_k(FArgs a)
{
  const int job = a.jobBase + blockIdx.z;
  const int cntj = (job==0) ? NTOK : a.cnt[job];
  const int mb = blockIdx.x, nb = blockIdx.y;
  if (mb*128 >= cntj) return;
  const ushort* list = (job==0) ? nullptr : a.lists + (size_t)(job-1)*NTOK;
  const ushort* B = (job<3) ? a.sw1+(size_t)job*FDIM*EDIM : a.gw1+(size_t)(job-3)*FDIM*EDIM;
  const float* bias = a.b1p + (size_t)job*FDIM;
  const size_t hoff = job_hoff(a, job);
  __shared__ __align__(16) ushort As[128*40];
  __shared__ __align__(16) ushort Bs[128*40];
  const int tid = threadIdx.x;
  const int lane = tid & 63, wave = tid >> 6;
  const int ar = tid >> 2, ac = tid & 3;
  const int row0 = mb*128 + ar, row1 = row0 + 64;
  const int t0 = list ? (int)list[min(row0,cntj-1)] : min(row0,cntj-1);
  const int t1 = list ? (int)list[min(row1,cntj-1)] : min(row1,cntj-1);
  const ushort* Ap0 = a.z + (size_t)t0*EDIM + ac*8;
  const ushort* Ap1 = a.z + (size_t)t1*EDIM + ac*8;
  const ushort* Bp0 = B + (size_t)(nb*128+ar)*EDIM + ac*8;
  const ushort* Bp1 = Bp0 + (size_t)64*EDIM;
  uint4 ra0 = *(const uint4*)(Ap0);
  uint4 ra1 = *(const uint4*)(Ap1);
  uint4 rb0 = *(const uint4*)(Bp0);
  uint4 rb1 = *(const uint4*)(Bp1);
  f32x4 acc[4][4];
  #pragma unroll
  for (int m=0;m<4;m++)
    #pragma unroll
    for (int n=0;n<4;n++) acc[m][n] = (f32x4){0.f,0.f,0.f,0.f};
  const int fr = lane & 15, fq = lane >> 4;
  const int rb_ = (wave>>1)*64, cb_ = (wave&1)*64;
  for (int kt=0; kt<24; ++kt){
    __syncthreads();
    *(uint4*)&As[ ar     *40 + ac*8] = ra0;
    *(uint4*)&As[(ar+64) *40 + ac*8] = ra1;
    *(uint4*)&Bs[ ar     *40 + ac*8] = rb0;
    *(uint4*)&Bs[(ar+64) *40 + ac*8] = rb1;
    if (kt+1 < 24){
      const int ko = (kt+1)*32;
      ra0 = *(const uint4*)(Ap0 + ko);
      ra1 = *(const uint4*)(Ap1 + ko);
      rb0 = *(const uint4*)(Bp0 + ko);
      rb1 = *(const uint4*)(Bp1 + ko);
    }
    __syncthreads();
    bf16x8 af[4], bfr[4];
    #pragma unroll
    for (int m=0;m<4;m++) af[m]  = *(const bf16x8*)&As[(rb_ + m*16 + fr)*40 + fq*8];
    #pragma unroll
    for (int n=0;n<4;n++) bfr[n] = *(const bf16x8*)&Bs[(cb_ + n*16 + fr)*40 + fq*8];
    #pragma unroll
    for (int m=0;m<4;m++)
      #pragma unroll
      for (int n=0;n<4;n++)
        acc[m][n] = __builtin_amdgcn_mfma_f32_16x16x32_bf16(af[m], bfr[n], acc[m][n], 0, 0, 0);
  }
  #pragma unroll
  for (int m=0;m<4;m++){
    #pragma unroll
    for (int j=0;j<4;j++){
      const int row = mb*128 + rb_ + m*16 + fq*4 + j;
      if (row < cntj){
        #pragma unroll
        for (int n=0;n<4;n++){
          const int col = nb*128 + cb_ + n*16 + fr;
          a.hidden[(hoff+row)*FDIM + col] = f2b(gelu_f(acc[m][n][j] + bias[col]));
        }
      }
    }
  }
}

// FFN2 / out-proj: atomic scatter-add GEMM, split-K=2. grid (64, 6, J*2) or (64,6,2) for jobBase=-1.
__global__ __launch_bounds__(256) void ffn2_k(FArgs a)
{
  const int zb = blockIdx.z;
  const bool op = (a.jobBase < 0);
  const int job = op ? -1 : a.jobBase + (zb>>1);
  const int ks = zb & 1;
  const int cntj = op ? NTOK : ((job==0) ? NTOK : a.cnt[job]);
  const int mb = blockIdx.x, nb = blockIdx.y;
  if (mb*128 >= cntj) return;
  const ushort* list = (op || job==0) ? nullptr : a.lists + (size_t)(job-1)*NTOK;
  const ushort* Abase; int lda; const ushort* B; const float* bias = nullptr;
  const float* coefp = nullptr; int eidx = 0; int kLen;
  if (op){ Abase = a.ctx; lda = EDIM; B = a.wo; kLen = EDIM/2; }
  else {
    lda = FDIM; kLen = FDIM/2;
    Abase = a.hidden + job_hoff(a, job)*FDIM;
    if (job<3){ B=a.sw2+(size_t)job*(size_t)EDIM*FDIM; bias=a.sb2+(size_t)job*EDIM; }
    else { eidx=job-3; B=a.gw2+(size_t)eidx*(size_t)EDIM*FDIM; bias=a.gb2+(size_t)eidx*EDIM; coefp=a.coef; }
  }
  const int kOff = ks*kLen;
  const int nst = kLen >> 5;
  __shared__ __align__(16) ushort As[128*40];
  __shared__ __align__(16) ushort Bs[128*40];
  const int tid = threadIdx.x;
  const int lane = tid & 63, wave = tid >> 6;
  const int ar = tid >> 2, ac = tid & 3;
  const int row0 = mb*128 + ar, row1 = row0 + 64;
  const ushort* Ap0 = Abase + (size_t)min(row0,cntj-1)*lda + kOff + ac*8;
  const ushort* Ap1 = Abase + (size_t)min(row1,cntj-1)*lda + kOff + ac*8;
  const ushort* Bp0 = B + (size_t)(nb*128+ar)*lda + kOff + ac*8;
  const ushort* Bp1 = Bp0 + (size_t)64*lda;
  uint4 ra0 = *(const uint4*)(Ap0);
  uint4 ra1 = *(const uint4*)(Ap1);
  uint4 rb0 = *(const uint4*)(Bp0);
  uint4 rb1 = *(const uint4*)(Bp1);
  f32x4 acc[4][4];
  #pragma unroll
  for (int m=0;m<4;m++)
    #pragma unroll
    for (int n=0;n<4;n++) acc[m][n] = (f32x4){0.f,0.f,0.f,0.f};
  const int fr = lane & 15, fq = lane >> 4;
  const int rb_ = (wave>>1)*64, cb_ = (wave&1)*64;
  for (int kt=0; kt<nst; ++kt){
    __syncthreads();
    *(uint4*)&As[ ar     *40 + ac*8] = ra0;
    *(uint4*)&As[(ar+64) *40 + ac*8] = ra1;
    *(uint4*)&Bs[ ar     *40 + ac*8] = rb0;
    *(uint4*)&Bs[(ar+64) *40 + ac*8] = rb1;
    if (kt+1 < nst){
      const int ko = (kt+1)*32;
      ra0 = *(const uint4*)(Ap0 + ko);
      ra1 = *(const uint4*)(Ap1 + ko);
      rb0 = *(const uint4*)(Bp0 + ko);
      rb1 = *(const uint4*)(Bp1 + ko);
    }
    __syncthreads();
    bf16x8 af[4], bfr[4];
    #pragma unroll
    for (int m=0;m<4;m++) af[m]  = *(const bf16x8*)&As[(rb_ + m*16 + fr)*40 + fq*8];
    #pragma unroll
    for (int n=0;n<4;n++) bfr[n] = *(const bf16x8*)&Bs[(cb_ + n*16 + fr)*40 + fq*8];
    #pragma unroll
    for (int m=0;m<4;m++)
      #pragma unroll
      for (int n=0;n<4;n++)
        acc[m][n] = __builtin_amdgcn_mfma_f32_16x16x32_bf16(af[m], bfr[n], acc[m][n], 0, 0, 0);
  }
  #pragma unroll
  for (int m=0;m<4;m++){
    #pragma unroll
    for (int j=0;j<4;j++){
      const int row = mb*128 + rb_ + m*16 + fq*4 + j;
      if (row < cntj){
        const int tok = list ? (int)list[row] : row;
        const float c = coefp ? coefp[(size_t)tok*8 + eidx] : 1.0f;
        #pragma unroll
        for (int n=0;n<4;n++){
          const int col = nb*128 + cb_ + n*16 + fr;
          float v = acc[m][n][j];
          if (bias && ks==0) v += bias[col];
          atomicAdd(&a.out[(size_t)tok*EDIM + col], c*v);
        }
      }
    }
  }
}

// ---------------- MFMA flash attention (unchanged) ----------------
__global__ __launch_bounds__(256) void attn_k(const ushort* __restrict__ qkv, ushort* __restrict__ ctx)
{
  const int qb = blockIdx.x, bh = blockIdx.y;
  const int b = bh/12, h = bh%12;
  const int tid = threadIdx.x;
  const int lane = tid & 63, w = tid >> 6;
  const int fr = lane & 15, fq = lane >> 4;
  __shared__ __align__(16) ushort Ks[4096];
  __shared__ __align__(16) ushort Vts[4096];
  __shared__ __align__(16) ushort Ps[4096];
  const size_t tokq = (size_t)b*1024 + (size_t)qb*64;

  bf16x8 qf[2];
  {
    const ushort* qp = qkv + (tokq + w*16 + fr)*2304 + h*64 + fq*8;
    qf[0] = *(const bf16x8*)(qp);
    qf[1] = *(const bf16x8*)(qp + 32);
  }
  f32x4 o[4];
  #pragma unroll
  for (int nt=0;nt<4;nt++) o[nt] = (f32x4){0.f,0.f,0.f,0.f};
  float m[4] = {-1e30f,-1e30f,-1e30f,-1e30f};
  float l[4] = {0.f,0.f,0.f,0.f};

  const int skr = tid>>3, skc = (tid&7)*8;
  const int svd = (tid&15)*4, svk = (tid>>4)*4;

  for (int kt=0; kt<16; ++kt){
    __syncthreads();
    const size_t tokk = (size_t)b*1024 + (size_t)kt*64;
    #pragma unroll
    for (int p=0;p<2;p++){
      int row = skr + p*32;
      uint4 kq = *(const uint4*)(qkv + (tokk+row)*2304 + 768 + h*64 + skc);
      *(uint4*)&Ks[row*64 + (skc ^ ((row&7)<<3))] = kq;
    }
    {
      union { ushort4 v4[4]; ushort s[16]; } tv;
      #pragma unroll
      for (int i=0;i<4;i++)
        tv.v4[i] = *(const ushort4*)(qkv + (tokk+svk+i)*2304 + 1536 + h*64 + svd);
      #pragma unroll
      for (int j=0;j<4;j++){
        ushort4 tj; tj.x=tv.s[j]; tj.y=tv.s[4+j]; tj.z=tv.s[8+j]; tj.w=tv.s[12+j];
        int dr = svd + j;
        *(ushort4*)&Vts[dr*64 + (svk ^ ((dr&7)<<3))] = tj;
      }
    }
    __syncthreads();
    f32x4 s[4];
    #pragma unroll
    for (int nt=0;nt<4;nt++){
      s[nt] = (f32x4){0.f,0.f,0.f,0.f};
      int kr = nt*16 + fr;
      const ushort* kb = &Ks[kr*64];
      int sw = (kr&7)<<3;
      bf16x8 k0 = *(const bf16x8*)&kb[(fq*8) ^ sw];
      bf16x8 k1 = *(const bf16x8*)&kb[(fq*8+32) ^ sw];
      s[nt] = __builtin_amdgcn_mfma_f32_16x16x32_bf16(qf[0], k0, s[nt], 0,0,0);
      s[nt] = __builtin_amdgcn_mfma_f32_16x16x32_bf16(qf[1], k1, s[nt], 0,0,0);
    }
    float a_[4], pr[4][4];
    #pragma unroll
    for (int j=0;j<4;j++){
      float mx = fmaxf(fmaxf(s[0][j],s[1][j]), fmaxf(s[2][j],s[3][j])) * 0.125f;
      mx = fmaxf(mx, __shfl_xor(mx,1));
      mx = fmaxf(mx, __shfl_xor(mx,2));
      mx = fmaxf(mx, __shfl_xor(mx,4));
      mx = fmaxf(mx, __shfl_xor(mx,8));
      float mn = fmaxf(m[j], mx);
      float a = __expf(m[j] - mn);
      m[j] = mn; a_[j] = a;
      float ss = 0.f;
      #pragma unroll
      for (int nt=0;nt<4;nt++){
        float p = __expf(s[nt][j]*0.125f - mn);
        pr[nt][j] = p; ss += p;
      }
      ss += __shfl_xor(ss,1);
      ss += __shfl_xor(ss,2);
      ss += __shfl_xor(ss,4);
      ss += __shfl_xor(ss,8);
      l[j] = l[j]*a + ss;
    }
    #pragma unroll
    for (int nt=0;nt<4;nt++){
      #pragma unroll
      for (int j=0;j<4;j++){
        int row = fq*4 + j;
        Ps[w*1024 + row*64 + ((nt*16+fr) ^ ((row&7)<<3))] = f2b(pr[nt][j]);
        o[nt][j] *= a_[j];
      }
    }
    #pragma unroll
    for (int ks=0; ks<2; ++ks){
      int kvo = ks*32 + fq*8;
      bf16x8 pf = *(const bf16x8*)&Ps[w*1024 + fr*64 + (kvo ^ ((fr&7)<<3))];
      #pragma unroll
      for (int nt=0;nt<4;nt++){
        int dr = nt*16 + fr;
        bf16x8 vf = *(const bf16x8*)&Vts[dr*64 + (kvo ^ ((dr&7)<<3))];
        o[nt] = __builtin_amdgcn_mfma_f32_16x16x32_bf16(pf, vf, o[nt], 0,0,0);
      }
    }
  }
  float inv[4];
  #pragma unroll
  for (int j=0;j<4;j++) inv[j] = 1.f/l[j];
  ushort* cp = ctx + (tokq + w*16)*768 + h*64;
  #pragma unroll
  for (int nt=0;nt<4;nt++){
    #pragma unroll
    for (int j=0;j<4;j++){
      cp[(size_t)(fq*4+j)*768 + nt*16 + fr] = f2b(o[nt][j]*inv[j]);
    }
  }
}

// ---------------- workspace layout ----------------
#define OFF_POOL   0u
#define OFF_Z      108527616u
#define OFF_COEF   121110528u
#define OFF_LISTS  121372672u   // ushort lists: 10*8192*2 = 163840
#define OFF_CNT    121536512u   // 256 B
#define OFF_B1P    121536768u   // 11*3072*4 = 135168 (ends 121671936 <= OFF_QKV)
#define OFF_QKV    121700608u
#define OFF_CTX    159449344u
#define OFF_XN1    172032256u
#define WS_GROUPED  222363904u   // OFF_QKV + 16384*3072*2

extern "C" void kernel_launch(void* const* d_in, const int* in_sizes, int n_in,
                              void* d_out, int out_size, void* d_ws, size_t ws_size,
                              hipStream_t stream)
{
  const float* x    = (const float*)d_in[0];
  const int*   mt   = (const int*)d_in[1];
  const float* n1g  = (const float*)d_in[2];
  const float* n1b  = (const float*)d_in[3];
  const float* n2g  = (const float*)d_in[4];
  const float* n2b  = (const float*)d_in[5];
  const float* wqkv = (const float*)d_in[6];
  const float* bqkv = (const float*)d_in[7];
  const float* wo   = (const float*)d_in[8];
  const float* bo   = (const float*)d_in[9];
  const float* rw   = (const float*)d_in[10];
  const float* rb   = (const float*)d_in[11];
  const float* slg  = (const float*)d_in[12];
  const float* slb  = (const float*)d_in[13];
  const float* sw1  = (const float*)d_in[14];
  const float* sb1  = (const float*)d_in[15];
  const float* sw2  = (const float*)d_in[16];
  const float* sb2  = (const float*)d_in[17];
  const float* glg  = (const float*)d_in[18];
  const float* glb  = (const float*)d_in[19];
  const float* gw1  = (const float*)d_in[20];
  const float* gb1  = (const float*)d_in[21];
  const float* gw2  = (const float*)d_in[22];
  const float* gb2  = (const float*)d_in[23];
  float* out = (float*)d_out;
  char* ws = (char*)d_ws;

  ushort* pool  = (ushort*)(ws + OFF_POOL);
  ushort* z     = (ushort*)(ws + OFF_Z);
  float*  coef  = (float*) (ws + OFF_COEF);
  ushort* lists = (ushort*)(ws + OFF_LISTS);
  int*    cnt   = (int*)   (ws + OFF_CNT);
  float*  b1p   = (float*) (ws + OFF_B1P);
  ushort* qkv   = (ushort*)(ws + OFF_QKV);
  ushort* ctx   = (ushort*)(ws + OFF_CTX);
  ushort* xn1   = (ushort*)(ws + OFF_XN1);
  ushort* hidden= (ushort*)(ws + OFF_QKV);   // aliases qkv/ctx/xn1 (dead by expert phase)

  ushort* pWqkv = pool + 0;
  ushort* pWo   = pool + 1769472;
  ushort* pSw1  = pool + 2359296;
  ushort* pSw2  = pool + 9437184;
  ushort* pGw1  = pool + 16515072;
  ushort* pGw2  = pool + 35389440;

  const bool grouped = (ws_size >= (size_t)WS_GROUPED);

  conv_w<<<52992, 256, 0, stream>>>(wqkv, wo, sw1, sw2, gw1, gw2, slg, glg, pool);
  b1fold_k<<<8448, 256, 0, stream>>>(sw1, gw1, sb1, gb1, slb, glb, b1p);
  ln1_k<<<2048, 256, 0, stream>>>(x, n1g, n1b, xn1);
  { GemmArgs a{}; a.A=xn1; a.B=pWqkv; a.bias=bqkv; a.outBF=qkv; a.K=768; a.ldc=2304;
    gemm_k<<<dim3(64,18),256,0,stream>>>(a); }
  attn_k<<<dim3(16,96),256,0,stream>>>(qkv, ctx);
  out_init<<<6144,256,0,stream>>>(x, bo, out);

  FArgs fa{};
  fa.z=z; fa.hidden=hidden; fa.ctx=ctx; fa.wo=pWo; fa.out=out;
  fa.lists=lists; fa.cnt=cnt; fa.coef=coef;
  fa.sw1=pSw1; fa.gw1=pGw1; fa.sw2=pSw2; fa.gw2=pGw2;
  fa.b1p=b1p; fa.sb2=sb2; fa.gb2=gb2;

  // out-proj: atomic split-K2 (out pre-filled with x + bo)
  { FArgs a = fa; a.jobBase = -1; a.compact = 0;
    ffn2_k<<<dim3(64,6,2),256,0,stream>>>(a); }

  ln2z_k<<<2048,256,0,stream>>>(out, n2g, n2b, z);
  router_k<<<2048,256,0,stream>>>(out, n2g, n2b, rw, rb, coef);
  build_lists<<<10,256,0,stream>>>(mt, coef, lists, cnt);

  if (grouped){
    { FArgs a = fa; a.jobBase = 0; a.compact = 1;
      ffn1_k<<<dim3(64,24,3),256,0,stream>>>(a);
      ffn2_k<<<dim3(64,6,6),256,0,stream>>>(a); }
    { FArgs a = fa; a.jobBase = 3; a.compact = 1;
      ffn1_k<<<dim3(64,24,8),256,0,stream>>>(a);
      ffn2_k<<<dim3(64,6,16),256,0,stream>>>(a); }
  } else {
    for (int j=0;j<11;j++){
      FArgs a = fa; a.jobBase = j; a.compact = 0;
      ffn1_k<<<dim3(64,24,1),256,0,stream>>>(a);
      ffn2_k<<<dim3(64,6,2),256,0,stream>>>(a);
    }
  }
}

// Round 6
// 1155.353 us; speedup vs baseline: 2.1528x; 1.0892x over previous
//
#include <hip/hip_runtime.h>
#include <cstdint>

#define NTOK 8192
#define EDIM 768
#define FDIM 3072

using bf16x8 = __attribute__((ext_vector_type(8))) __bf16;
using f32x4  = __attribute__((ext_vector_type(4))) float;

__device__ __forceinline__ float b2f(ushort u){ union{uint32_t i; float f;} v; v.i = ((uint32_t)u)<<16; return v.f; }
__device__ __forceinline__ ushort f2b(float f){ union{float f; uint32_t i;} v; v.f=f; uint32_t r = v.i + 0x7fffu + ((v.i>>16)&1u); return (ushort)(r>>16); }
// fast GELU: x * sigmoid(1.5957691x + 0.0713548x^3); |err vs exact| ~3e-4 << bf16 rounding of hidden
__device__ __forceinline__ float gelu_f(float v){
  float c = v*(1.5957691216f + 0.0713548162726f*v*v);
  return v / (1.f + __expf(-c));
}

// ---------------- weight fp32 -> bf16 pool (LN gains folded into W1 rows) ----------------
__global__ __launch_bounds__(256) void conv_w(const float* w0,const float* w1,const float* w2,
                                              const float* w3,const float* w4,const float* w5,
                                              const float* slg, const float* glg,
                                              ushort* pool)
{
  size_t idx4 = (size_t)blockIdx.x*256 + threadIdx.x;
  size_t e = idx4*4;
  const float* src; size_t base; int region;
  if      (e <  1769472u){src=w0;base=0;        region=0;}
  else if (e <  2359296u){src=w1;base=1769472u; region=1;}
  else if (e <  9437184u){src=w2;base=2359296u; region=2;}
  else if (e < 16515072u){src=w3;base=9437184u; region=3;}
  else if (e < 35389440u){src=w4;base=16515072u;region=4;}
  else                   {src=w5;base=35389440u;region=5;}
  size_t within = e - base;
  f32x4 f = *(const f32x4*)(src + within);
  if (region==2){
    int ex = (int)(within/2359296u); int col = (int)(within%768u);
    f32x4 g = *(const f32x4*)(slg + ex*768 + col);
    f[0]*=g[0]; f[1]*=g[1]; f[2]*=g[2]; f[3]*=g[3];
  } else if (region==4){
    int ex = (int)(within/2359296u); int col = (int)(within%768u);
    f32x4 g = *(const f32x4*)(glg + ex*768 + col);
    f[0]*=g[0]; f[1]*=g[1]; f[2]*=g[2]; f[3]*=g[3];
  }
  ushort4 u; u.x=f2b(f[0]); u.y=f2b(f[1]); u.z=f2b(f[2]); u.w=f2b(f[3]);
  *(ushort4*)(pool+e) = u;
}

// b1p[j*FDIM+f] = b1[j][f] + W1[j][f][:] . lb[j][:]   (11 experts: 3 spec + 8 gen)
__global__ __launch_bounds__(256) void b1fold_k(const float* __restrict__ sw1, const float* __restrict__ gw1,
                                                const float* __restrict__ sb1, const float* __restrict__ gb1,
                                                const float* __restrict__ slb, const float* __restrict__ glb,
                                                float* __restrict__ b1p)
{
  int j = blockIdx.x*4 + (threadIdx.x>>6);   // 0 .. 11*3072-1
  int lane = threadIdx.x & 63;
  int je = j / FDIM, f = j % FDIM;
  const float* wrow = (je<3) ? sw1 + ((size_t)je*FDIM + f)*EDIM : gw1 + ((size_t)(je-3)*FDIM + f)*EDIM;
  const float* lb   = (je<3) ? slb + (size_t)je*EDIM : glb + (size_t)(je-3)*EDIM;
  float s = 0.f;
  #pragma unroll
  for (int i=0;i<12;i++){ int d = lane + 64*i; s += wrow[d]*lb[d]; }
  #pragma unroll
  for (int o=32;o>0;o>>=1) s += __shfl_xor(s,o);
  if (lane==0){
    float base = (je<3) ? sb1[je*FDIM+f] : gb1[(je-3)*FDIM+f];
    b1p[j] = base + s;
  }
}

// out = x + bo[col]
__global__ __launch_bounds__(256) void out_init(const float* __restrict__ x, const float* __restrict__ bo,
                                                float* __restrict__ out)
{
  size_t i = ((size_t)blockIdx.x*256 + threadIdx.x)*4;
  int col = (int)(i % EDIM);
  f32x4 xv = *(const f32x4*)(x+i);
  f32x4 bv = *(const f32x4*)(bo+col);
  f32x4 r = { xv[0]+bv[0], xv[1]+bv[1], xv[2]+bv[2], xv[3]+bv[3] };
  *(f32x4*)(out+i) = r;
}

// ---------------- LayerNorm kernels (wave per token) ----------------
__global__ __launch_bounds__(256) void ln1_k(const float* __restrict__ x, const float* __restrict__ g,
                                             const float* __restrict__ b, ushort* __restrict__ out)
{
  int w = blockIdx.x*4 + (threadIdx.x>>6);
  int lane = threadIdx.x & 63;
  const float* xr = x + (size_t)w*EDIM;
  float v[12]; float s=0.f, s2=0.f;
  #pragma unroll
  for (int i=0;i<12;i++){ v[i]=xr[lane+64*i]; s+=v[i]; s2+=v[i]*v[i]; }
  #pragma unroll
  for (int o=32;o>0;o>>=1){ s += __shfl_xor(s,o); s2 += __shfl_xor(s2,o); }
  float mu = s*(1.f/768.f);
  float rs = rsqrtf(s2*(1.f/768.f) - mu*mu + 1e-5f);
  ushort* op = out + (size_t)w*EDIM;
  #pragma unroll
  for (int i=0;i<12;i++){ int d=lane+64*i; op[d] = f2b((v[i]-mu)*rs*g[d] + b[d]); }
}

// fused: LN2(out) -> z (second LN core) AND router coef  (one pass over out)
__global__ __launch_bounds__(256) void lnr_k(const float* __restrict__ x1, const float* __restrict__ g2,
                                             const float* __restrict__ b2, const float* __restrict__ rw,
                                             const float* __restrict__ rbv,
                                             ushort* __restrict__ z, float* __restrict__ coef)
{
  int w = blockIdx.x*4 + (threadIdx.x>>6);
  int lane = threadIdx.x & 63;
  const float* xr = x1 + (size_t)w*EDIM;
  float v[12]; float s=0.f, s2=0.f;
  #pragma unroll
  for (int i=0;i<12;i++){ v[i]=xr[lane+64*i]; s+=v[i]; s2+=v[i]*v[i]; }
  #pragma unroll
  for (int o=32;o>0;o>>=1){ s += __shfl_xor(s,o); s2 += __shfl_xor(s2,o); }
  float mu = s*(1.f/768.f);
  float rs = rsqrtf(s2*(1.f/768.f) - mu*mu + 1e-5f);
  float xn[12]; s=0.f; s2=0.f;
  #pragma unroll
  for (int i=0;i<12;i++){ int d=lane+64*i; xn[i]=(v[i]-mu)*rs*g2[d]+b2[d]; s+=xn[i]; s2+=xn[i]*xn[i]; }
  // router logits on xn (fp32, matches reference selection)
  float pl[8] = {0.f,0.f,0.f,0.f,0.f,0.f,0.f,0.f};
  #pragma unroll
  for (int i=0;i<12;i++){
    int d=lane+64*i; float xv=xn[i];
    #pragma unroll
    for (int e=0;e<8;e++) pl[e] += xv * rw[e*EDIM + d];
  }
  #pragma unroll
  for (int o=32;o>0;o>>=1){ s += __shfl_xor(s,o); s2 += __shfl_xor(s2,o); }
  float mu2 = s*(1.f/768.f);
  float rs2 = rsqrtf(s2*(1.f/768.f) - mu2*mu2 + 1e-5f);
  ushort* op = z + (size_t)w*EDIM;
  #pragma unroll
  for (int i=0;i<12;i++){ int d=lane+64*i; op[d] = f2b((xn[i]-mu2)*rs2); }
  #pragma unroll
  for (int e=0;e<8;e++){
    #pragma unroll
    for (int o=32;o>0;o>>=1) pl[e] += __shfl_xor(pl[e], o);
  }
  float lgt[8]; float mx = -1e30f;
  #pragma unroll
  for (int e=0;e<8;e++){ lgt[e]=pl[e]+rbv[e]; mx = fmaxf(mx, lgt[e]); }
  float p[8]; float den=0.f;
  #pragma unroll
  for (int e=0;e<8;e++){ p[e]=__expf(lgt[e]-mx); den+=p[e]; }
  float inv = 1.f/den;
  #pragma unroll
  for (int e=0;e<8;e++) p[e]*=inv;
  int i1=0;
  #pragma unroll
  for (int e=1;e<8;e++) if (p[e]>p[i1]) i1=e;
  int i2=(i1==0)?1:0;
  #pragma unroll
  for (int e=0;e<8;e++){ if (e==i1) continue; if (p[e]>p[i2]) i2=e; }
  float w1 = 1.f/(1.f+__expf(p[i2]-p[i1]));
  float w2 = 1.f - w1;
  if (lane < 8){
    float c = (lane==i1)? w1 : ((lane==i2)? w2 : 0.f);
    coef[(size_t)w*8 + lane] = c;
  }
}

// deterministic gather lists via block-wide prefix sums (no atomics); lists are ushort (tok < 8192)
__global__ __launch_bounds__(256) void build_lists(const int* __restrict__ mt, const float* __restrict__ coef,
                                                   ushort* __restrict__ lists, int* __restrict__ cnt)
{
  const int job = blockIdx.x;       // 0: mt==0, 1: mt==1, 2..9: general expert job-2
  ushort* list = lists + (size_t)job*NTOK;
  __shared__ int wsum[4];
  int base = 0;
  const int lane = threadIdx.x & 63, wv = threadIdx.x >> 6;
  for (int c0=0; c0<NTOK; c0+=256){
    int t = c0 + threadIdx.x;
    bool flag;
    if (job==0)      flag = (mt[t]==0);
    else if (job==1) flag = (mt[t]==1);
    else             flag = (coef[(size_t)t*8 + (job-2)] != 0.0f);
    unsigned long long bal = __ballot(flag);
    int pre = __popcll(bal & ((1ull<<lane)-1ull));
    if (lane==0) wsum[wv] = __popcll(bal);
    __syncthreads();
    int off = base + pre;
    for (int k=0;k<wv;k++) off += wsum[k];
    int tot = wsum[0]+wsum[1]+wsum[2]+wsum[3];
    if (flag) list[off] = (ushort)t;
    base += tot;
    __syncthreads();
  }
  if (threadIdx.x==0){ cnt[job+1] = base; if (job==0) cnt[0] = NTOK; }
}

// ---------------- dense MFMA GEMM (QKV): C = A@B^T + bias -> bf16 ----------------
struct GemmArgs {
  const ushort* A; const ushort* B;
  const float* bias;
  ushort* outBF;
  int K, ldc;
};

__global__ __launch_bounds__(256) void gemm_k(GemmArgs g)
{
  const int mb = blockIdx.x, nb = blockIdx.y;
  __shared__ __align__(16) ushort As[128*40];
  __shared__ __align__(16) ushort Bs[128*40];
  const int tid = threadIdx.x;
  const int lane = tid & 63, wave = tid >> 6;
  const int ar = tid >> 2, ac = tid & 3;
  const int row0 = mb*128 + ar, row1 = row0 + 64;
  const int KK = g.K;
  const ushort* Ap0 = g.A + (size_t)row0*KK + ac*8;
  const ushort* Ap1 = g.A + (size_t)row1*KK + ac*8;
  const ushort* Bp0 = g.B + (size_t)(nb*128+ar)*KK + ac*8;
  const ushort* Bp1 = Bp0 + (size_t)64*KK;
  const int nst = KK >> 5;
  uint4 ra0 = *(const uint4*)(Ap0);
  uint4 ra1 = *(const uint4*)(Ap1);
  uint4 rb0 = *(const uint4*)(Bp0);
  uint4 rb1 = *(const uint4*)(Bp1);
  f32x4 acc[4][4];
  #pragma unroll
  for (int m=0;m<4;m++)
    #pragma unroll
    for (int n=0;n<4;n++) acc[m][n] = (f32x4){0.f,0.f,0.f,0.f};
  const int fr = lane & 15, fq = lane >> 4;
  const int rb_ = (wave>>1)*64, cb_ = (wave&1)*64;
  for (int kt=0; kt<nst; ++kt){
    __syncthreads();
    *(uint4*)&As[ ar     *40 + ac*8] = ra0;
    *(uint4*)&As[(ar+64) *40 + ac*8] = ra1;
    *(uint4*)&Bs[ ar     *40 + ac*8] = rb0;
    *(uint4*)&Bs[(ar+64) *40 + ac*8] = rb1;
    if (kt+1 < nst){
      const int ko = (kt+1)*32;
      ra0 = *(const uint4*)(Ap0 + ko);
      ra1 = *(const uint4*)(Ap1 + ko);
      rb0 = *(const uint4*)(Bp0 + ko);
      rb1 = *(const uint4*)(Bp1 + ko);
    }
    __syncthreads();
    bf16x8 af[4], bfr[4];
    #pragma unroll
    for (int m=0;m<4;m++) af[m]  = *(const bf16x8*)&As[(rb_ + m*16 + fr)*40 + fq*8];
    #pragma unroll
    for (int n=0;n<4;n++) bfr[n] = *(const bf16x8*)&Bs[(cb_ + n*16 + fr)*40 + fq*8];
    #pragma unroll
    for (int m=0;m<4;m++)
      #pragma unroll
      for (int n=0;n<4;n++)
        acc[m][n] = __builtin_amdgcn_mfma_f32_16x16x32_bf16(af[m], bfr[n], acc[m][n], 0, 0, 0);
  }
  #pragma unroll
  for (int m=0;m<4;m++){
    #pragma unroll
    for (int j=0;j<4;j++){
      const int row = mb*128 + rb_ + m*16 + fq*4 + j;
      #pragma unroll
      for (int n=0;n<4;n++){
        const int col = nb*128 + cb_ + n*16 + fr;
        g.outBF[(size_t)row*g.ldc + col] = f2b(acc[m][n][j] + g.bias[col]);
      }
    }
  }
}

// ---------------- grouped expert FFN kernels ----------------
struct FArgs {
  const ushort* z; ushort* hidden; const ushort* ctx; const ushort* wo;
  float* out;
  const ushort* lists; const int* cnt; const float* coef;
  const ushort* sw1; const ushort* gw1; const ushort* sw2; const ushort* gw2;
  const float* b1p; const float* sb2; const float* gb2;
  int jobBase; int compact;
};

__device__ __forceinline__ size_t job_hoff(const FArgs& a, int job){
  size_t h = 0;
  if (a.compact){
    if (job==1) h = NTOK;
    else if (job==2) h = NTOK + (size_t)a.cnt[1];
    else if (job>=3){ for (int k=3;k<job;k++) h += (size_t)a.cnt[k]; }
  }
  return h;
}

// FFN1: hidden[hoff+row] = gelu( z[tok] @ W1'^T + b1p ), grid (64,24,J); W1' has lg folded, b1p has lb folded
__global__ __launch_bounds__(256) void ffn1_k(FArgs a)
{
  const int job = a.jobBase + blockIdx.z;
  const int cntj = (job==0) ? NTOK : a.cnt[job];
  const int mb = blockIdx.x, nb = blockIdx.y;
  if (mb*128 >= cntj) return;
  const ushort* list = (job==0) ? nullptr : a.lists + (size_t)(job-1)*NTOK;
  const ushort* B = (job<3) ? a.sw1+(size_t)job*FDIM*EDIM : a.gw1+(size_t)(job-3)*FDIM*EDIM;
  const float* bias = a.b1p + (size_t)job*FDIM;
  const size_t hoff = job_hoff(a, job);
  __shared__ __align__(16) ushort As[128*40];
  __shared__ __align__(16) ushort Bs[128*40];
  const int tid = threadIdx.x;
  const int lane = tid & 63, wave = tid >> 6;
  const int ar = tid >> 2, ac = tid & 3;
  const int row0 = mb*128 + ar, row1 = row0 + 64;
  const int t0 = list ? (int)list[min(row0,cntj-1)] : min(row0,cntj-1);
  const int t1 = list ? (int)list[min(row1,cntj-1)] : min(row1,cntj-1);
  const ushort* Ap0 = a.z + (size_t)t0*EDIM + ac*8;
  const ushort* Ap1 = a.z + (size_t)t1*EDIM + ac*8;
  const ushort* Bp0 = B + (size_t)(nb*128+ar)*EDIM + ac*8;
  const ushort* Bp1 = Bp0 + (size_t)64*EDIM;
  uint4 ra0 = *(const uint4*)(Ap0);
  uint4 ra1 = *(const uint4*)(Ap1);
  uint4 rb0 = *(const uint4*)(Bp0);
  uint4 rb1 = *(const uint4*)(Bp1);
  f32x4 acc[4][4];
  #pragma unroll
  for (int m=0;m<4;m++)
    #pragma unroll
    for (int n=0;n<4;n++) acc[m][n] = (f32x4){0.f,0.f,0.f,0.f};
  const int fr = lane & 15, fq = lane >> 4;
  const int rb_ = (wave>>1)*64, cb_ = (wave&1)*64;
  for (int kt=0; kt<24; ++kt){
    __syncthreads();
    *(uint4*)&As[ ar     *40 + ac*8] = ra0;
    *(uint4*)&As[(ar+64) *40 + ac*8] = ra1;
    *(uint4*)&Bs[ ar     *40 + ac*8] = rb0;
    *(uint4*)&Bs[(ar+64) *40 + ac*8] = rb1;
    if (kt+1 < 24){
      const int ko = (kt+1)*32;
      ra0 = *(const uint4*)(Ap0 + ko);
      ra1 = *(const uint4*)(Ap1 + ko);
      rb0 = *(const uint4*)(Bp0 + ko);
      rb1 = *(const uint4*)(Bp1 + ko);
    }
    __syncthreads();
    bf16x8 af[4], bfr[4];
    #pragma unroll
    for (int m=0;m<4;m++) af[m]  = *(const bf16x8*)&As[(rb_ + m*16 + fr)*40 + fq*8];
    #pragma unroll
    for (int n=0;n<4;n++) bfr[n] = *(const bf16x8*)&Bs[(cb_ + n*16 + fr)*40 + fq*8];
    #pragma unroll
    for (int m=0;m<4;m++)
      #pragma unroll
      for (int n=0;n<4;n++)
        acc[m][n] = __builtin_amdgcn_mfma_f32_16x16x32_bf16(af[m], bfr[n], acc[m][n], 0, 0, 0);
  }
  #pragma unroll
  for (int m=0;m<4;m++){
    #pragma unroll
    for (int j=0;j<4;j++){
      const int row = mb*128 + rb_ + m*16 + fq*4 + j;
      if (row < cntj){
        #pragma unroll
        for (int n=0;n<4;n++){
          const int col = nb*128 + cb_ + n*16 + fr;
          a.hidden[(hoff+row)*FDIM + col] = f2b(gelu_f(acc[m][n][j] + bias[col]));
        }
      }
    }
  }
}

// FFN2 / out-proj: atomic scatter-add GEMM, split-K=2. grid (64, 6, J*2) or (64,6,2) for jobBase=-1.
__global__ __launch_bounds__(256) void ffn2_k(FArgs a)
{
  const int zb = blockIdx.z;
  const bool op = (a.jobBase < 0);
  const int job = op ? -1 : a.jobBase + (zb>>1);
  const int ks = zb & 1;
  const int cntj = op ? NTOK : ((job==0) ? NTOK : a.cnt[job]);
  const int mb = blockIdx.x, nb = blockIdx.y;
  if (mb*128 >= cntj) return;
  const ushort* list = (op || job==0) ? nullptr : a.lists + (size_t)(job-1)*NTOK;
  const ushort* Abase; int lda; const ushort* B; const float* bias = nullptr;
  const float* coefp = nullptr; int eidx = 0; int kLen;
  if (op){ Abase = a.ctx; lda = EDIM; B = a.wo; kLen = EDIM/2; }
  else {
    lda = FDIM; kLen = FDIM/2;
    Abase = a.hidden + job_hoff(a, job)*FDIM;
    if (job<3){ B=a.sw2+(size_t)job*(size_t)EDIM*FDIM; bias=a.sb2+(size_t)job*EDIM; }
    else { eidx=job-3; B=a.gw2+(size_t)eidx*(size_t)EDIM*FDIM; bias=a.gb2+(size_t)eidx*EDIM; coefp=a.coef; }
  }
  const int kOff = ks*kLen;
  const int nst = kLen >> 5;
  __shared__ __align__(16) ushort As[128*40];
  __shared__ __align__(16) ushort Bs[128*40];
  const int tid = threadIdx.x;
  const int lane = tid & 63, wave = tid >> 6;
  const int ar = tid >> 2, ac = tid & 3;
  const int row0 = mb*128 + ar, row1 = row0 + 64;
  const ushort* Ap0 = Abase + (size_t)min(row0,cntj-1)*lda + kOff + ac*8;
  const ushort* Ap1 = Abase + (size_t)min(row1,cntj-1)*lda + kOff + ac*8;
  const ushort* Bp0 = B + (size_t)(nb*128+ar)*lda + kOff + ac*8;
  const ushort* Bp1 = Bp0 + (size_t)64*lda;
  uint4 ra0 = *(const uint4*)(Ap0);
  uint4 ra1 = *(const uint4*)(Ap1);
  uint4 rb0 = *(const uint4*)(Bp0);
  uint4 rb1 = *(const uint4*)(Bp1);
  f32x4 acc[4][4];
  #pragma unroll
  for (int m=0;m<4;m++)
    #pragma unroll
    for (int n=0;n<4;n++) acc[m][n] = (f32x4){0.f,0.f,0.f,0.f};
  const int fr = lane & 15, fq = lane >> 4;
  const int rb_ = (wave>>1)*64, cb_ = (wave&1)*64;
  for (int kt=0; kt<nst; ++kt){
    __syncthreads();
    *(uint4*)&As[ ar     *40 + ac*8] = ra0;
    *(uint4*)&As[(ar+64) *40 + ac*8] = ra1;
    *(uint4*)&Bs[ ar     *40 + ac*8] = rb0;
    *(uint4*)&Bs[(ar+64) *40 + ac*8] = rb1;
    if (kt+1 < nst){
      const int ko = (kt+1)*32;
      ra0 = *(const uint4*)(Ap0 + ko);
      ra1 = *(const uint4*)(Ap1 + ko);
      rb0 = *(const uint4*)(Bp0 + ko);
      rb1 = *(const uint4*)(Bp1 + ko);
    }
    __syncthreads();
    bf16x8 af[4], bfr[4];
    #pragma unroll
    for (int m=0;m<4;m++) af[m]  = *(const bf16x8*)&As[(rb_ + m*16 + fr)*40 + fq*8];
    #pragma unroll
    for (int n=0;n<4;n++) bfr[n] = *(const bf16x8*)&Bs[(cb_ + n*16 + fr)*40 + fq*8];
    #pragma unroll
    for (int m=0;m<4;m++)
      #pragma unroll
      for (int n=0;n<4;n++)
        acc[m][n] = __builtin_amdgcn_mfma_f32_16x16x32_bf16(af[m], bfr[n], acc[m][n], 0, 0, 0);
  }
  #pragma unroll
  for (int m=0;m<4;m++){
    #pragma unroll
    for (int j=0;j<4;j++){
      const int row = mb*128 + rb_ + m*16 + fq*4 + j;
      if (row < cntj){
        const int tok = list ? (int)list[row] : row;
        const float c = coefp ? coefp[(size_t)tok*8 + eidx] : 1.0f;
        #pragma unroll
        for (int n=0;n<4;n++){
          const int col = nb*128 + cb_ + n*16 + fr;
          float v = acc[m][n][j];
          if (bias && ks==0) v += bias[col];
          atomicAdd(&a.out[(size_t)tok*EDIM + col], c*v);
        }
      }
    }
  }
}

// ---------------- MFMA flash attention (unchanged) ----------------
__global__ __launch_bounds__(256) void attn_k(const ushort* __restrict__ qkv, ushort* __restrict__ ctx)
{
  const int qb = blockIdx.x, bh = blockIdx.y;
  const int b = bh/12, h = bh%12;
  const int tid = threadIdx.x;
  const int lane = tid & 63, w = tid >> 6;
  const int fr = lane & 15, fq = lane >> 4;
  __shared__ __align__(16) ushort Ks[4096];
  __shared__ __align__(16) ushort Vts[4096];
  __shared__ __align__(16) ushort Ps[4096];
  const size_t tokq = (size_t)b*1024 + (size_t)qb*64;

  bf16x8 qf[2];
  {
    const ushort* qp = qkv + (tokq + w*16 + fr)*2304 + h*64 + fq*8;
    qf[0] = *(const bf16x8*)(qp);
    qf[1] = *(const bf16x8*)(qp + 32);
  }
  f32x4 o[4];
  #pragma unroll
  for (int nt=0;nt<4;nt++) o[nt] = (f32x4){0.f,0.f,0.f,0.f};
  float m[4] = {-1e30f,-1e30f,-1e30f,-1e30f};
  float l[4] = {0.f,0.f,0.f,0.f};

  const int skr = tid>>3, skc = (tid&7)*8;
  const int svd = (tid&15)*4, svk = (tid>>4)*4;

  for (int kt=0; kt<16; ++kt){
    __syncthreads();
    const size_t tokk = (size_t)b*1024 + (size_t)kt*64;
    #pragma unroll
    for (int p=0;p<2;p++){
      int row = skr + p*32;
      uint4 kq = *(const uint4*)(qkv + (tokk+row)*2304 + 768 + h*64 + skc);
      *(uint4*)&Ks[row*64 + (skc ^ ((row&7)<<3))] = kq;
    }
    {
      union { ushort4 v4[4]; ushort s[16]; } tv;
      #pragma unroll
      for (int i=0;i<4;i++)
        tv.v4[i] = *(const ushort4*)(qkv + (tokk+svk+i)*2304 + 1536 + h*64 + svd);
      #pragma unroll
      for (int j=0;j<4;j++){
        ushort4 tj; tj.x=tv.s[j]; tj.y=tv.s[4+j]; tj.z=tv.s[8+j]; tj.w=tv.s[12+j];
        int dr = svd + j;
        *(ushort4*)&Vts[dr*64 + (svk ^ ((dr&7)<<3))] = tj;
      }
    }
    __syncthreads();
    f32x4 s[4];
    #pragma unroll
    for (int nt=0;nt<4;nt++){
      s[nt] = (f32x4){0.f,0.f,0.f,0.f};
      int kr = nt*16 + fr;
      const ushort* kb = &Ks[kr*64];
      int sw = (kr&7)<<3;
      bf16x8 k0 = *(const bf16x8*)&kb[(fq*8) ^ sw];
      bf16x8 k1 = *(const bf16x8*)&kb[(fq*8+32) ^ sw];
      s[nt] = __builtin_amdgcn_mfma_f32_16x16x32_bf16(qf[0], k0, s[nt], 0,0,0);
      s[nt] = __builtin_amdgcn_mfma_f32_16x16x32_bf16(qf[1], k1, s[nt], 0,0,0);
    }
    float a_[4], pr[4][4];
    #pragma unroll
    for (int j=0;j<4;j++){
      float mx = fmaxf(fmaxf(s[0][j],s[1][j]), fmaxf(s[2][j],s[3][j])) * 0.125f;
      mx = fmaxf(mx, __shfl_xor(mx,1));
      mx = fmaxf(mx, __shfl_xor(mx,2));
      mx = fmaxf(mx, __shfl_xor(mx,4));
      mx = fmaxf(mx, __shfl_xor(mx,8));
      float mn = fmaxf(m[j], mx);
      float a = __expf(m[j] - mn);
      m[j] = mn; a_[j] = a;
      float ss = 0.f;
      #pragma unroll
      for (int nt=0;nt<4;nt++){
        float p = __expf(s[nt][j]*0.125f - mn);
        pr[nt][j] = p; ss += p;
      }
      ss += __shfl_xor(ss,1);
      ss += __shfl_xor(ss,2);
      ss += __shfl_xor(ss,4);
      ss += __shfl_xor(ss,8);
      l[j] = l[j]*a + ss;
    }
    #pragma unroll
    for (int nt=0;nt<4;nt++){
      #pragma unroll
      for (int j=0;j<4;j++){
        int row = fq*4 + j;
        Ps[w*1024 + row*64 + ((nt*16+fr) ^ ((row&7)<<3))] = f2b(pr[nt][j]);
        o[nt][j] *= a_[j];
      }
    }
    #pragma unroll
    for (int ks=0; ks<2; ++ks){
      int kvo = ks*32 + fq*8;
      bf16x8 pf = *(const bf16x8*)&Ps[w*1024 + fr*64 + (kvo ^ ((fr&7)<<3))];
      #pragma unroll
      for (int nt=0;nt<4;nt++){
        int dr = nt*16 + fr;
        bf16x8 vf = *(const bf16x8*)&Vts[dr*64 + (kvo ^ ((dr&7)<<3))];
        o[nt] = __builtin_amdgcn_mfma_f32_16x16x32_bf16(pf, vf, o[nt], 0,0,0);
      }
    }
  }
  float inv[4];
  #pragma unroll
  for (int j=0;j<4;j++) inv[j] = 1.f/l[j];
  ushort* cp = ctx + (tokq + w*16)*768 + h*64;
  #pragma unroll
  for (int nt=0;nt<4;nt++){
    #pragma unroll
    for (int j=0;j<4;j++){
      cp[(size_t)(fq*4+j)*768 + nt*16 + fr] = f2b(o[nt][j]*inv[j]);
    }
  }
}

// ---------------- workspace layout ----------------
#define OFF_POOL   0u
#define OFF_Z      108527616u
#define OFF_COEF   121110528u
#define OFF_LISTS  121372672u   // ushort lists: 10*8192*2 = 163840
#define OFF_CNT    121536512u   // 256 B
#define OFF_B1P    121536768u   // 11*3072*4 = 135168
#define OFF_QKV    121700608u
#define OFF_CTX    159449344u
#define OFF_XN1    172032256u
#define WS_GROUPED  222363904u   // OFF_QKV + 16384*3072*2

extern "C" void kernel_launch(void* const* d_in, const int* in_sizes, int n_in,
                              void* d_out, int out_size, void* d_ws, size_t ws_size,
                              hipStream_t stream)
{
  const float* x    = (const float*)d_in[0];
  const int*   mt   = (const int*)d_in[1];
  const float* n1g  = (const float*)d_in[2];
  const float* n1b  = (const float*)d_in[3];
  const float* n2g  = (const float*)d_in[4];
  const float* n2b  = (const float*)d_in[5];
  const float* wqkv = (const float*)d_in[6];
  const float* bqkv = (const float*)d_in[7];
  const float* wo   = (const float*)d_in[8];
  const float* bo   = (const float*)d_in[9];
  const float* rw   = (const float*)d_in[10];
  const float* rb   = (const float*)d_in[11];
  const float* slg  = (const float*)d_in[12];
  const float* slb  = (const float*)d_in[13];
  const float* sw1  = (const float*)d_in[14];
  const float* sb1  = (const float*)d_in[15];
  const float* sw2  = (const float*)d_in[16];
  const float* sb2  = (const float*)d_in[17];
  const float* glg  = (const float*)d_in[18];
  const float* glb  = (const float*)d_in[19];
  const float* gw1  = (const float*)d_in[20];
  const float* gb1  = (const float*)d_in[21];
  const float* gw2  = (const float*)d_in[22];
  const float* gb2  = (const float*)d_in[23];
  float* out = (float*)d_out;
  char* ws = (char*)d_ws;

  ushort* pool  = (ushort*)(ws + OFF_POOL);
  ushort* z     = (ushort*)(ws + OFF_Z);
  float*  coef  = (float*) (ws + OFF_COEF);
  ushort* lists = (ushort*)(ws + OFF_LISTS);
  int*    cnt   = (int*)   (ws + OFF_CNT);
  float*  b1p   = (float*) (ws + OFF_B1P);
  ushort* qkv   = (ushort*)(ws + OFF_QKV);
  ushort* ctx   = (ushort*)(ws + OFF_CTX);
  ushort* xn1   = (ushort*)(ws + OFF_XN1);
  ushort* hidden= (ushort*)(ws + OFF_QKV);   // aliases qkv/ctx/xn1 (dead by expert phase)

  ushort* pWqkv = pool + 0;
  ushort* pWo   = pool + 1769472;
  ushort* pSw1  = pool + 2359296;
  ushort* pSw2  = pool + 9437184;
  ushort* pGw1  = pool + 16515072;
  ushort* pGw2  = pool + 35389440;

  const bool grouped = (ws_size >= (size_t)WS_GROUPED);

  conv_w<<<52992, 256, 0, stream>>>(wqkv, wo, sw1, sw2, gw1, gw2, slg, glg, pool);
  b1fold_k<<<8448, 256, 0, stream>>>(sw1, gw1, sb1, gb1, slb, glb, b1p);
  ln1_k<<<2048, 256, 0, stream>>>(x, n1g, n1b, xn1);
  { GemmArgs a{}; a.A=xn1; a.B=pWqkv; a.bias=bqkv; a.outBF=qkv; a.K=768; a.ldc=2304;
    gemm_k<<<dim3(64,18),256,0,stream>>>(a); }
  attn_k<<<dim3(16,96),256,0,stream>>>(qkv, ctx);
  out_init<<<6144,256,0,stream>>>(x, bo, out);

  FArgs fa{};
  fa.z=z; fa.hidden=hidden; fa.ctx=ctx; fa.wo=pWo; fa.out=out;
  fa.lists=lists; fa.cnt=cnt; fa.coef=coef;
  fa.sw1=pSw1; fa.gw1=pGw1; fa.sw2=pSw2; fa.gw2=pGw2;
  fa.b1p=b1p; fa.sb2=sb2; fa.gb2=gb2;

  // out-proj: atomic split-K2 (out pre-filled with x + bo)
  { FArgs a = fa; a.jobBase = -1; a.compact = 0;
    ffn2_k<<<dim3(64,6,2),256,0,stream>>>(a); }

  lnr_k<<<2048,256,0,stream>>>(out, n2g, n2b, rw, rb, z, coef);
  build_lists<<<10,256,0,stream>>>(mt, coef, lists, cnt);

  if (grouped){
    { FArgs a = fa; a.jobBase = 0; a.compact = 1;
      ffn1_k<<<dim3(64,24,3),256,0,stream>>>(a);
      ffn2_k<<<dim3(64,6,6),256,0,stream>>>(a); }
    { FArgs a = fa; a.jobBase = 3; a.compact = 1;
      ffn1_k<<<dim3(64,24,8),256,0,stream>>>(a);
      ffn2_k<<<dim3(64,6,16),256,0,stream>>>(a); }
  } else {
    for (int j=0;j<11;j++){
      FArgs a = fa; a.jobBase = j; a.compact = 0;
      ffn1_k<<<dim3(64,24,1),256,0,stream>>>(a);
      ffn2_k<<<dim3(64,6,2),256,0,stream>>>(a);
    }
  }
}